// Round 6
// baseline (564.705 us; speedup 1.0000x reference)
//
#include <hip/hip_runtime.h>
#include <math.h>

constexpr int Nn  = 65536;    // nodes
constexpr int Ne  = 1048576;  // edges
constexpr int Bg  = 256;      // graphs
constexpr int DIN = 32;
constexpr int D   = 64;

typedef __attribute__((ext_vector_type(8))) short bf16x8;
typedef __attribute__((ext_vector_type(4))) float f32x4;

__device__ __forceinline__ float sigf(float x) { return 1.0f / (1.0f + expf(-x)); }

// ---- bf16 split helpers (RNE) ----
__device__ __forceinline__ unsigned short bf16_rne(float f) {
  unsigned u = __float_as_uint(f);
  unsigned r = u + 0x7FFFu + ((u >> 16) & 1u);
  return (unsigned short)(r >> 16);
}
__device__ __forceinline__ float bf16_tof(unsigned short h) {
  return __uint_as_float(((unsigned)h) << 16);
}
__device__ __forceinline__ void split2(float f, unsigned short& hi, unsigned short& lo) {
  hi = bf16_rne(f);
  lo = bf16_rne(f - bf16_tof(hi));
}

#define MFMA(a, b, c) __builtin_amdgcn_mfma_f32_16x16x32_bf16(a, b, c, 0, 0, 0)

// ---------------------------------------------------------------------------
// Merged prep: weight fragment packing (idx < 36864) + small transposes.
// pack index p = ((nt*KS + ks)*64 + L)*8 + j  (separate hi/lo planes)
// ---------------------------------------------------------------------------
__global__ void k_prepw(const float* __restrict__ W_mlp, const float* __restrict__ W_conv,
                        const float* __restrict__ gWih, const float* __restrict__ gWhh,
                        const float* __restrict__ lW_ih, const float* __restrict__ lW_hh,
                        const float* __restrict__ W1,
                        unsigned short* __restrict__ mlp_h, unsigned short* __restrict__ mlp_l,
                        unsigned short* __restrict__ cv_h,  unsigned short* __restrict__ cv_l,
                        unsigned short* __restrict__ ih_h,  unsigned short* __restrict__ ih_l,
                        unsigned short* __restrict__ hh_h,  unsigned short* __restrict__ hh_l,
                        float* __restrict__ WihT, float* __restrict__ WhhT,
                        float* __restrict__ W1T) {
  int idx = blockIdx.x * 256 + threadIdx.x;
  if (idx < 36864) {
    const float* W; int K, KS; unsigned short *oh, *ol; int lp = idx;
    if (idx < 2048)       { W = W_mlp;  K = 32; KS = 1; oh = mlp_h; ol = mlp_l; }
    else if (idx < 6144)  { W = W_conv; K = 64; KS = 2; oh = cv_h;  ol = cv_l;  lp -= 2048; }
    else if (idx < 24576) { W = gWih;   K = 96; KS = 3; oh = ih_h;  ol = ih_l;  lp -= 6144; }
    else                  { W = gWhh;   K = 64; KS = 2; oh = hh_h;  ol = hh_l;  lp -= 24576; }
    int j = lp & 7, lane = (lp >> 3) & 63, q = lp >> 9;
    int ks = q % KS, nt = q / KS;
    int n = nt * 16 + (lane & 15);
    int k = ks * 32 + (lane >> 4) * 8 + j;
    unsigned short hi, lo;
    split2(W[n * K + k], hi, lo);
    oh[lp] = hi; ol[lp] = lo;
    return;
  }
  int t = idx - 36864;
  if (t < 32768) {                 // lstm W_ih [256][128] -> WihT [128][256]
    int row = t / 128, k = t % 128;
    WihT[k * 256 + row] = lW_ih[t];
  } else if (t < 49152) {          // lstm W_hh [256][64] -> WhhT [64][256]
    int j = t - 32768;
    int row = j / 64, k = j % 64;
    WhhT[k * 256 + row] = lW_hh[j];
  } else if (t < 57344) {          // W1 [64][128] -> W1T [128][64]
    int j = t - 49152;
    int row = j / 128, k = j % 128;
    W1T[k * 64 + row] = W1[j];
  }
}

// ---------------------------------------------------------------------------
// x prep: fill inp96 x-columns (64..95) split planes
// ---------------------------------------------------------------------------
__global__ void k_prepx(const float* __restrict__ x,
                        unsigned short* __restrict__ Aih, unsigned short* __restrict__ Ail) {
  int idx = blockIdx.x * 256 + threadIdx.x;
  if (idx >= Nn * DIN) return;
  int n = idx >> 5, c = idx & 31;
  unsigned short hi, lo;
  split2(x[idx], hi, lo);
  Aih[(size_t)n * 96 + 64 + c] = hi;
  Ail[(size_t)n * 96 + 64 + c] = lo;
}

// ---------------------------------------------------------------------------
// conv1: h = x @ W_mlp^T + b  (K=32, N=64). Splits x in-kernel.
// ---------------------------------------------------------------------------
__global__ __launch_bounds__(256) void k_conv1(const float* __restrict__ x,
                                               const unsigned short* __restrict__ Wh,
                                               const unsigned short* __restrict__ Wl,
                                               const float* __restrict__ bias,
                                               float* __restrict__ h,
                                               unsigned short* __restrict__ hph,
                                               unsigned short* __restrict__ hpl) {
  int wave = threadIdx.x >> 6, lane = threadIdx.x & 63;
  int quad = lane >> 4;
  int n0w = blockIdx.x * 64 + wave * 16;
  int rowA = n0w + (lane & 15);
  const float4* xp = (const float4*)&x[(size_t)rowA * 32 + quad * 8];
  float4 xa = xp[0], xb = xp[1];
  float xv[8] = {xa.x, xa.y, xa.z, xa.w, xb.x, xb.y, xb.z, xb.w};
  bf16x8 ah, al;
#pragma unroll
  for (int j = 0; j < 8; ++j) {
    unsigned short hi, lo; split2(xv[j], hi, lo);
    ah[j] = (short)hi; al[j] = (short)lo;
  }
  f32x4 acc[4] = {};
#pragma unroll
  for (int nt = 0; nt < 4; ++nt) {
    bf16x8 bh = *(const bf16x8*)&Wh[(nt * 64 + lane) * 8];
    bf16x8 bl = *(const bf16x8*)&Wl[(nt * 64 + lane) * 8];
    acc[nt] = MFMA(ah, bh, acc[nt]);
    acc[nt] = MFMA(ah, bl, acc[nt]);
    acc[nt] = MFMA(al, bh, acc[nt]);
  }
  int col0 = lane & 15;
#pragma unroll
  for (int nt = 0; nt < 4; ++nt) {
    float bv = bias[nt * 16 + col0];
#pragma unroll
    for (int r = 0; r < 4; ++r) {
      int node = n0w + quad * 4 + r;
      float v = acc[nt][r] + bv;
      size_t o = (size_t)node * 64 + nt * 16 + col0;
      h[o] = v;
      unsigned short hi, lo; split2(v, hi, lo);
      hph[o] = hi; hpl[o] = lo;
    }
  }
}

// ---------------------------------------------------------------------------
// lin = h @ W_conv^T + b  (K=64, N=64).  fp32 out.
// ---------------------------------------------------------------------------
__global__ __launch_bounds__(256) void k_lin(const unsigned short* __restrict__ Ah,
                                             const unsigned short* __restrict__ Al,
                                             const unsigned short* __restrict__ Wh,
                                             const unsigned short* __restrict__ Wl,
                                             const float* __restrict__ bias,
                                             float* __restrict__ lin) {
  int wave = threadIdx.x >> 6, lane = threadIdx.x & 63;
  int quad = lane >> 4;
  int n0w = blockIdx.x * 64 + wave * 16;
  int rowA = n0w + (lane & 15);
  f32x4 acc[4] = {};
#pragma unroll
  for (int ks = 0; ks < 2; ++ks) {
    bf16x8 ah = *(const bf16x8*)&Ah[(size_t)rowA * 64 + ks * 32 + quad * 8];
    bf16x8 al = *(const bf16x8*)&Al[(size_t)rowA * 64 + ks * 32 + quad * 8];
#pragma unroll
    for (int nt = 0; nt < 4; ++nt) {
      bf16x8 bh = *(const bf16x8*)&Wh[((nt * 2 + ks) * 64 + lane) * 8];
      bf16x8 bl = *(const bf16x8*)&Wl[((nt * 2 + ks) * 64 + lane) * 8];
      acc[nt] = MFMA(ah, bh, acc[nt]);
      acc[nt] = MFMA(ah, bl, acc[nt]);
      acc[nt] = MFMA(al, bh, acc[nt]);
    }
  }
  int col0 = lane & 15;
#pragma unroll
  for (int nt = 0; nt < 4; ++nt) {
    float bv = bias[nt * 16 + col0];
#pragma unroll
    for (int r = 0; r < 4; ++r) {
      int node = n0w + quad * 4 + r;
      lin[(size_t)node * 64 + nt * 16 + col0] = acc[nt][r] + bv;
    }
  }
}

// ---------------------------------------------------------------------------
// Fused GRU step with LDS-staged weight fragments (round-5 structure).
// ---------------------------------------------------------------------------
__global__ __launch_bounds__(256) void k_gru(const unsigned short* __restrict__ Aih,
                                             const unsigned short* __restrict__ Ail,
                                             const unsigned short* __restrict__ Hh,
                                             const unsigned short* __restrict__ Hl,
                                             const unsigned short* __restrict__ Wih_h,
                                             const unsigned short* __restrict__ Wih_l,
                                             const unsigned short* __restrict__ Whh_h,
                                             const unsigned short* __restrict__ Whh_l,
                                             const float* __restrict__ b_ih,
                                             const float* __restrict__ b_hh,
                                             const float* __restrict__ h_old,
                                             float* __restrict__ h_new,
                                             unsigned short* __restrict__ hph,
                                             unsigned short* __restrict__ hpl) {
  __shared__ unsigned short sW[12288];  // hi[12][64][8] | lo[12][64][8]
  int tid = threadIdx.x;
  int wave = tid >> 6, lane = tid & 63;
  int quad = lane >> 4;
  int n0w = blockIdx.x * 64 + wave * 16;
  int rowA = n0w + (lane & 15);
  f32x4 acc[12] = {};   // gi r,z,n; gh r,z folded into [0..7]
  f32x4 accN2[4] = {};  // gh n-gate

  for (int ks = 0; ks < 3; ++ks) {
    __syncthreads();
    for (int i = tid; i < 768; i += 256) {
      int nt = i >> 6, r = i & 63;
      *(bf16x8*)&sW[i * 8] = *(const bf16x8*)&Wih_h[((nt * 3 + ks) * 64 + r) * 8];
      *(bf16x8*)&sW[6144 + i * 8] = *(const bf16x8*)&Wih_l[((nt * 3 + ks) * 64 + r) * 8];
    }
    __syncthreads();
    bf16x8 ah = *(const bf16x8*)&Aih[(size_t)rowA * 96 + ks * 32 + quad * 8];
    bf16x8 al = *(const bf16x8*)&Ail[(size_t)rowA * 96 + ks * 32 + quad * 8];
#pragma unroll
    for (int nt = 0; nt < 12; ++nt) {
      bf16x8 bh = *(const bf16x8*)&sW[(nt * 64 + lane) * 8];
      bf16x8 bl = *(const bf16x8*)&sW[6144 + (nt * 64 + lane) * 8];
      acc[nt] = MFMA(ah, bh, acc[nt]);
      acc[nt] = MFMA(ah, bl, acc[nt]);
      acc[nt] = MFMA(al, bh, acc[nt]);
    }
  }
  for (int ks = 0; ks < 2; ++ks) {
    __syncthreads();
    for (int i = tid; i < 768; i += 256) {
      int nt = i >> 6, r = i & 63;
      *(bf16x8*)&sW[i * 8] = *(const bf16x8*)&Whh_h[((nt * 2 + ks) * 64 + r) * 8];
      *(bf16x8*)&sW[6144 + i * 8] = *(const bf16x8*)&Whh_l[((nt * 2 + ks) * 64 + r) * 8];
    }
    __syncthreads();
    bf16x8 ah = *(const bf16x8*)&Hh[(size_t)rowA * 64 + ks * 32 + quad * 8];
    bf16x8 al = *(const bf16x8*)&Hl[(size_t)rowA * 64 + ks * 32 + quad * 8];
#pragma unroll
    for (int nt = 0; nt < 12; ++nt) {
      bf16x8 bh = *(const bf16x8*)&sW[(nt * 64 + lane) * 8];
      bf16x8 bl = *(const bf16x8*)&sW[6144 + (nt * 64 + lane) * 8];
      if (nt < 8) {
        acc[nt] = MFMA(ah, bh, acc[nt]);
        acc[nt] = MFMA(ah, bl, acc[nt]);
        acc[nt] = MFMA(al, bh, acc[nt]);
      } else {
        accN2[nt - 8] = MFMA(ah, bh, accN2[nt - 8]);
        accN2[nt - 8] = MFMA(ah, bl, accN2[nt - 8]);
        accN2[nt - 8] = MFMA(al, bh, accN2[nt - 8]);
      }
    }
  }

  int col0 = lane & 15;
#pragma unroll
  for (int nt = 0; nt < 4; ++nt) {
    float br  = b_ih[nt * 16 + col0]       + b_hh[nt * 16 + col0];
    float bz  = b_ih[64 + nt * 16 + col0]  + b_hh[64 + nt * 16 + col0];
    float bin = b_ih[128 + nt * 16 + col0];
    float bhn = b_hh[128 + nt * 16 + col0];
#pragma unroll
    for (int r = 0; r < 4; ++r) {
      int node = n0w + quad * 4 + r;
      size_t o = (size_t)node * 64 + nt * 16 + col0;
      float rr = sigf(acc[nt][r] + br);
      float zz = sigf(acc[nt + 4][r] + bz);
      float nn = tanhf(acc[nt + 8][r] + bin + rr * (accN2[nt][r] + bhn));
      float hv = (1.f - zz) * nn + zz * h_old[o];
      h_new[o] = hv;
      unsigned short hi, lo; split2(hv, hi, lo);
      hph[o] = hi; hpl[o] = lo;
    }
  }
}

// ---------------------------------------------------------------------------
// CSR build
// ---------------------------------------------------------------------------
__global__ void k_hist(const int* __restrict__ eidx, int* __restrict__ count) {
  int t = blockIdx.x * 256 + threadIdx.x;
  if (t < Ne) atomicAdd(&count[eidx[Ne + t]], 1);
}

// scan (1024 threads) + graphptr (first 257 threads) merged
__global__ __launch_bounds__(1024) void k_scan(const int* __restrict__ count,
                                               int* __restrict__ rp,
                                               int* __restrict__ cursor,
                                               const int* __restrict__ batch,
                                               int* __restrict__ gp) {
  __shared__ int sh[1024];
  int t = threadIdx.x;
  if (t <= Bg) {
    int lo = 0, hi = Nn;
    while (lo < hi) {
      int mid = (lo + hi) >> 1;
      if (batch[mid] < t) lo = mid + 1; else hi = mid;
    }
    gp[t] = lo;
  }
  int base = t * 64;
  int sum = 0;
  for (int i = 0; i < 64; ++i) sum += count[base + i];
  sh[t] = sum;
  __syncthreads();
  for (int off = 1; off < 1024; off <<= 1) {
    int v = (t >= off) ? sh[t - off] : 0;
    __syncthreads();
    sh[t] += v;
    __syncthreads();
  }
  int run = (t == 0) ? 0 : sh[t - 1];
  for (int i = 0; i < 64; ++i) {
    int c = count[base + i];
    rp[base + i] = run;
    cursor[base + i] = run;
    run += c;
  }
  if (t == 1023) rp[Nn] = run;
}

// single pass; nontemporal scatter store -> no L2 allocate, combines in MALL
__global__ void k_place(const int* __restrict__ eidx, int* __restrict__ cursor,
                        int* __restrict__ srcs) {
  int t = blockIdx.x * 256 + threadIdx.x;
  if (t < Ne) {
    int d = eidx[Ne + t];
    int p = atomicAdd(&cursor[d], 1);
    __builtin_nontemporal_store(eidx[t], &srcs[p]);
  }
}

// ---------------------------------------------------------------------------
// CSR aggregate: m[n] = sum over in-edges of lin[src]; writes split planes.
// ---------------------------------------------------------------------------
__global__ void k_aggregate(const int* __restrict__ rp, const int* __restrict__ srcs,
                            const float* __restrict__ lin,
                            unsigned short* __restrict__ Aih,
                            unsigned short* __restrict__ Ail) {
  int t = blockIdx.x * 256 + threadIdx.x;
  int n = t >> 4;
  int q = t & 15;
  int s = rp[n], e = rp[n + 1];
  float4 acc = {0.f, 0.f, 0.f, 0.f};
  for (int i = s; i < e; ++i) {
    int src = srcs[i];
    float4 v = *(const float4*)&lin[(size_t)src * 64 + q * 4];
    acc.x += v.x; acc.y += v.y; acc.z += v.z; acc.w += v.w;
  }
  ushort4 h4, l4;
  split2(acc.x, h4.x, l4.x);
  split2(acc.y, h4.y, l4.y);
  split2(acc.z, h4.z, l4.z);
  split2(acc.w, h4.w, l4.w);
  *(ushort4*)&Aih[(size_t)n * 96 + q * 4] = h4;
  *(ushort4*)&Ail[(size_t)n * 96 + q * 4] = l4;
}

// ---------------------------------------------------------------------------
// Set2Set: LSTM cell (per-graph block).
// ---------------------------------------------------------------------------
__global__ __launch_bounds__(256) void k_lstm(float* __restrict__ q_star,
                                              float* __restrict__ hl,
                                              float* __restrict__ cl,
                                              const float* __restrict__ WihT,
                                              const float* __restrict__ WhhT,
                                              const float* __restrict__ b_ih,
                                              const float* __restrict__ b_hh) {
  int g = blockIdx.x, t = threadIdx.x;
  __shared__ float qs[128], hsh[64], gates[256];
  if (t < 128) qs[t] = q_star[g * 128 + t];
  else if (t < 192) hsh[t - 128] = hl[g * 64 + (t - 128)];
  __syncthreads();
  float acc = b_ih[t] + b_hh[t];
  for (int k = 0; k < 128; ++k) acc = fmaf(WihT[k * 256 + t], qs[k], acc);
  for (int k = 0; k < 64; ++k)  acc = fmaf(WhhT[k * 256 + t], hsh[k], acc);
  gates[t] = acc;
  __syncthreads();
  if (t < 64) {
    float ig = sigf(gates[t]),        fg = sigf(gates[64 + t]);
    float gg = tanhf(gates[128 + t]), og = sigf(gates[192 + t]);
    float c = fg * cl[g * 64 + t] + ig * gg;
    float q = og * tanhf(c);
    cl[g * 64 + t] = c;
    hl[g * 64 + t] = q;
    q_star[g * 128 + t] = q;
  }
}

// ---------------------------------------------------------------------------
// Fused attention: per-graph block.  Phase A: e_i = h[i].q (16 lanes/node,
// scores to LDS).  Phase B: segment max.  Phase C: softmax-weighted sum.
// ---------------------------------------------------------------------------
constexpr int ACAP = 1024;  // max nodes per graph (dataset max ~330)
__global__ __launch_bounds__(256) void k_attn(const float* __restrict__ h,
                                              const int* __restrict__ gp,
                                              float* __restrict__ q_star) {
  int g = blockIdx.x;
  int t = threadIdx.x;
  int w = t >> 6, lane = t & 63;
  __shared__ float eL[ACAP];
  __shared__ float red[4];
  __shared__ float partial[4][64];
  __shared__ float asum_p[4];
  __shared__ float emax_sh;
  int s = gp[g], e = gp[g + 1];
  int cnt = e - s;

  // phase A: dot products, 4 nodes per wave-iteration (16 lanes each)
  float4 qv = *(const float4*)&q_star[g * 128 + (lane & 15) * 4];
  for (int i0 = s + w * 4; i0 < e; i0 += 16) {
    int node = i0 + (lane >> 4);
    float p = 0.f;
    if (node < e) {
      float4 o = *(const float4*)&h[(size_t)node * 64 + (lane & 15) * 4];
      p = o.x * qv.x + o.y * qv.y + o.z * qv.z + o.w * qv.w;
    }
    p += __shfl_xor(p, 1); p += __shfl_xor(p, 2);
    p += __shfl_xor(p, 4); p += __shfl_xor(p, 8);
    if (node < e && (lane & 15) == 0) eL[node - s] = p;
  }
  __syncthreads();

  // phase B: max over eL
  float m = -INFINITY;
  for (int i = t; i < cnt; i += 256) m = fmaxf(m, eL[i]);
#pragma unroll
  for (int o = 32; o >= 1; o >>= 1) m = fmaxf(m, __shfl_xor(m, o));
  if (lane == 0) red[w] = m;
  __syncthreads();
  if (t == 0) {
    float mm = fmaxf(fmaxf(red[0], red[1]), fmaxf(red[2], red[3]));
    emax_sh = isfinite(mm) ? mm : 0.f;
  }
  __syncthreads();
  float emax = emax_sh;

  // phase C: weighted feature sum (lane = dim, wave-strided nodes)
  float acc = 0.f, asum = 0.f;
  for (int i = s + w; i < e; i += 4) {
    float a = expf(eL[i - s] - emax);
    asum += a;
    acc = fmaf(a, h[(size_t)i * 64 + lane], acc);
  }
  partial[w][lane] = acc;
  if (lane == 0) asum_p[w] = asum;
  __syncthreads();
  if (t < 64) {
    float r  = partial[0][t] + partial[1][t] + partial[2][t] + partial[3][t];
    float as = asum_p[0] + asum_p[1] + asum_p[2] + asum_p[3];
    q_star[g * 128 + 64 + t] = (cnt > 0) ? r / fmaxf(as, 1e-16f) : 0.f;
  }
}

// ---------------------------------------------------------------------------
// Head
// ---------------------------------------------------------------------------
__global__ __launch_bounds__(64) void k_head(const float* __restrict__ q_star,
                                             const float* __restrict__ W1T,
                                             const float* __restrict__ b1,
                                             const float* __restrict__ W2,
                                             const float* __restrict__ b2,
                                             float* __restrict__ outp) {
  int g = blockIdx.x;
  int lane = threadIdx.x;
  __shared__ float qsh[128];
  __shared__ float hsh[64];
  __shared__ float l4[4];
  qsh[lane] = q_star[g * 128 + lane];
  qsh[64 + lane] = q_star[g * 128 + 64 + lane];
  __syncthreads();
  float acc = b1[lane];
  for (int k = 0; k < 128; ++k) acc = fmaf(W1T[k * 64 + lane], qsh[k], acc);
  hsh[lane] = fmaxf(acc, 0.f);
  __syncthreads();
  if (lane < 4) {
    float lg = b2[lane];
    for (int d = 0; d < 64; ++d) lg = fmaf(W2[lane * 64 + d], hsh[d], lg);
    l4[lane] = lg;
  }
  __syncthreads();
  if (lane < 4) {
    float m = fmaxf(fmaxf(l4[0], l4[1]), fmaxf(l4[2], l4[3]));
    float ssum = expf(l4[0] - m) + expf(l4[1] - m) + expf(l4[2] - m) + expf(l4[3] - m);
    outp[g * 4 + lane] = l4[lane] - m - logf(ssum);
  }
}

// ---------------------------------------------------------------------------
extern "C" void kernel_launch(void* const* d_in, const int* in_sizes, int n_in,
                              void* d_out, int out_size, void* d_ws, size_t ws_size,
                              hipStream_t stream) {
  const float* x        = (const float*)d_in[0];
  const int*   eidx     = (const int*)d_in[1];
  const int*   batch    = (const int*)d_in[2];
  const float* W_mlp    = (const float*)d_in[3];
  const float* b_mlp    = (const float*)d_in[4];
  const float* W_conv   = (const float*)d_in[5];
  const float* b_conv   = (const float*)d_in[6];
  const float* gW_ih    = (const float*)d_in[7];
  const float* gW_hh    = (const float*)d_in[8];
  const float* gb_ih    = (const float*)d_in[9];
  const float* gb_hh    = (const float*)d_in[10];
  const float* lW_ih    = (const float*)d_in[11];
  const float* lW_hh    = (const float*)d_in[12];
  const float* lb_ih    = (const float*)d_in[13];
  const float* lb_hh    = (const float*)d_in[14];
  const float* W1       = (const float*)d_in[15];
  const float* b1       = (const float*)d_in[16];
  const float* W2       = (const float*)d_in[17];
  const float* b2       = (const float*)d_in[18];
  float* outp = (float*)d_out;

  // ---- workspace layout ----
  char* ws = (char*)d_ws;
  size_t off = 0;
  auto alloc = [&](size_t bytes) { size_t r = off; off = (off + bytes + 255) & ~(size_t)255; return r; };
  float* hA  = (float*)(ws + alloc((size_t)Nn * 64 * 4));
  float* hB  = (float*)(ws + alloc((size_t)Nn * 64 * 4));
  unsigned short* hpAh = (unsigned short*)(ws + alloc((size_t)Nn * 64 * 2));
  unsigned short* hpAl = (unsigned short*)(ws + alloc((size_t)Nn * 64 * 2));
  unsigned short* hpBh = (unsigned short*)(ws + alloc((size_t)Nn * 64 * 2));
  unsigned short* hpBl = (unsigned short*)(ws + alloc((size_t)Nn * 64 * 2));
  unsigned short* Aih  = (unsigned short*)(ws + alloc((size_t)Nn * 96 * 2));
  unsigned short* Ail  = (unsigned short*)(ws + alloc((size_t)Nn * 96 * 2));
  float* lin   = (float*)(ws + alloc((size_t)Nn * 64 * 4));
  int*   count = (int*)(ws + alloc((size_t)Nn * 4));
  int*   rp    = (int*)(ws + alloc((size_t)(Nn + 1) * 4));
  int*   cursor= (int*)(ws + alloc((size_t)Nn * 4));
  int*   srcs  = (int*)(ws + alloc((size_t)Ne * 4));
  int*   gp    = (int*)(ws + alloc((size_t)(Bg + 1) * 4));
  float* WihT  = (float*)(ws + alloc((size_t)128 * 256 * 4));
  float* WhhT  = (float*)(ws + alloc((size_t)64 * 256 * 4));
  float* W1T   = (float*)(ws + alloc((size_t)128 * 64 * 4));
  unsigned short* mlp_h = (unsigned short*)(ws + alloc(2048 * 2));
  unsigned short* mlp_l = (unsigned short*)(ws + alloc(2048 * 2));
  unsigned short* cv_h  = (unsigned short*)(ws + alloc(4096 * 2));
  unsigned short* cv_l  = (unsigned short*)(ws + alloc(4096 * 2));
  unsigned short* ih_h  = (unsigned short*)(ws + alloc(18432 * 2));
  unsigned short* ih_l  = (unsigned short*)(ws + alloc(18432 * 2));
  unsigned short* hh_h  = (unsigned short*)(ws + alloc(12288 * 2));
  unsigned short* hh_l  = (unsigned short*)(ws + alloc(12288 * 2));
  float* s2s   = (float*)(ws + alloc((size_t)Bg * (128 + 64 + 64) * 4));
  float* q_star = s2s;
  float* hl     = s2s + Bg * 128;
  float* cl     = s2s + Bg * 128 + Bg * 64;
  (void)in_sizes; (void)n_in; (void)out_size; (void)ws_size;

  hipMemsetAsync(count, 0, (size_t)Nn * 4, stream);
  hipMemsetAsync(s2s, 0, (size_t)Bg * 256 * 4, stream);

  // CSR build + prep
  k_hist<<<Ne / 256, 256, 0, stream>>>(eidx, count);
  k_scan<<<1, 1024, 0, stream>>>(count, rp, cursor, batch, gp);
  k_place<<<Ne / 256, 256, 0, stream>>>(eidx, cursor, srcs);
  k_prepw<<<368, 256, 0, stream>>>(W_mlp, W_conv, gW_ih, gW_hh, lW_ih, lW_hh, W1,
                                   mlp_h, mlp_l, cv_h, cv_l, ih_h, ih_l, hh_h, hh_l,
                                   WihT, WhhT, W1T);
  k_prepx<<<Nn * DIN / 256, 256, 0, stream>>>(x, Aih, Ail);

  // conv1
  k_conv1<<<Nn / 64, 256, 0, stream>>>(x, mlp_h, mlp_l, b_mlp, hA, hpAh, hpAl);

  float* h = hA; float* h2 = hB;
  unsigned short *cph = hpAh, *cpl = hpAl, *nph = hpBh, *npl = hpBl;
  for (int step = 0; step < 2; ++step) {
    k_lin<<<Nn / 64, 256, 0, stream>>>(cph, cpl, cv_h, cv_l, b_conv, lin);
    k_aggregate<<<Nn * 16 / 256, 256, 0, stream>>>(rp, srcs, lin, Aih, Ail);
    k_gru<<<Nn / 64, 256, 0, stream>>>(Aih, Ail, cph, cpl, ih_h, ih_l, hh_h, hh_l,
                                       gb_ih, gb_hh, h, h2, nph, npl);
    float* tf = h; h = h2; h2 = tf;
    unsigned short* tu;
    tu = cph; cph = nph; nph = tu;
    tu = cpl; cpl = npl; npl = tu;
  }

  for (int it = 0; it < 3; ++it) {
    k_lstm<<<Bg, 256, 0, stream>>>(q_star, hl, cl, WihT, WhhT, lb_ih, lb_hh);
    k_attn<<<Bg, 256, 0, stream>>>(h, gp, q_star);
  }
  k_head<<<Bg, 64, 0, stream>>>(q_star, W1T, b1, W2, b2, outp);
}

// Round 7
// 429.954 us; speedup vs baseline: 1.3134x; 1.3134x over previous
//
#include <hip/hip_runtime.h>
#include <math.h>

constexpr int Nn  = 65536;    // nodes
constexpr int Ne  = 1048576;  // edges
constexpr int Bg  = 256;      // graphs
constexpr int DIN = 32;
constexpr int D   = 64;

constexpr int NB   = 256;     // dst buckets (dst>>8)
constexpr int BCAP = 6144;    // bucket stream capacity (mean 4096, +36 sigma)

typedef __attribute__((ext_vector_type(8))) short bf16x8;
typedef __attribute__((ext_vector_type(4))) float f32x4;

__device__ __forceinline__ float sigf(float x) { return 1.0f / (1.0f + expf(-x)); }

// ---- bf16 split helpers (RNE) ----
__device__ __forceinline__ unsigned short bf16_rne(float f) {
  unsigned u = __float_as_uint(f);
  unsigned r = u + 0x7FFFu + ((u >> 16) & 1u);
  return (unsigned short)(r >> 16);
}
__device__ __forceinline__ float bf16_tof(unsigned short h) {
  return __uint_as_float(((unsigned)h) << 16);
}
__device__ __forceinline__ void split2(float f, unsigned short& hi, unsigned short& lo) {
  hi = bf16_rne(f);
  lo = bf16_rne(f - bf16_tof(hi));
}

#define MFMA(a, b, c) __builtin_amdgcn_mfma_f32_16x16x32_bf16(a, b, c, 0, 0, 0)

// ---------------------------------------------------------------------------
// Merged prep: weight fragment packing (idx < 36864) + small transposes.
// ---------------------------------------------------------------------------
__global__ void k_prepw(const float* __restrict__ W_mlp, const float* __restrict__ W_conv,
                        const float* __restrict__ gWih, const float* __restrict__ gWhh,
                        const float* __restrict__ lW_ih, const float* __restrict__ lW_hh,
                        const float* __restrict__ W1,
                        unsigned short* __restrict__ mlp_h, unsigned short* __restrict__ mlp_l,
                        unsigned short* __restrict__ cv_h,  unsigned short* __restrict__ cv_l,
                        unsigned short* __restrict__ ih_h,  unsigned short* __restrict__ ih_l,
                        unsigned short* __restrict__ hh_h,  unsigned short* __restrict__ hh_l,
                        float* __restrict__ WihT, float* __restrict__ WhhT,
                        float* __restrict__ W1T) {
  int idx = blockIdx.x * 256 + threadIdx.x;
  if (idx < 36864) {
    const float* W; int K, KS; unsigned short *oh, *ol; int lp = idx;
    if (idx < 2048)       { W = W_mlp;  K = 32; KS = 1; oh = mlp_h; ol = mlp_l; }
    else if (idx < 6144)  { W = W_conv; K = 64; KS = 2; oh = cv_h;  ol = cv_l;  lp -= 2048; }
    else if (idx < 24576) { W = gWih;   K = 96; KS = 3; oh = ih_h;  ol = ih_l;  lp -= 6144; }
    else                  { W = gWhh;   K = 64; KS = 2; oh = hh_h;  ol = hh_l;  lp -= 24576; }
    int j = lp & 7, lane = (lp >> 3) & 63, q = lp >> 9;
    int ks = q % KS, nt = q / KS;
    int n = nt * 16 + (lane & 15);
    int k = ks * 32 + (lane >> 4) * 8 + j;
    unsigned short hi, lo;
    split2(W[n * K + k], hi, lo);
    oh[lp] = hi; ol[lp] = lo;
    return;
  }
  int t = idx - 36864;
  if (t < 32768) {                 // lstm W_ih [256][128] -> WihT [128][256]
    int row = t / 128, k = t % 128;
    WihT[k * 256 + row] = lW_ih[t];
  } else if (t < 49152) {          // lstm W_hh [256][64] -> WhhT [64][256]
    int j = t - 32768;
    int row = j / 64, k = j % 64;
    WhhT[k * 256 + row] = lW_hh[j];
  } else if (t < 57344) {          // W1 [64][128] -> W1T [128][64]
    int j = t - 49152;
    int row = j / 128, k = j % 128;
    W1T[k * 64 + row] = W1[j];
  }
}

// ---------------------------------------------------------------------------
// x prep: fill inp96 x-columns (64..95) split planes
// ---------------------------------------------------------------------------
__global__ void k_prepx(const float* __restrict__ x,
                        unsigned short* __restrict__ Aih, unsigned short* __restrict__ Ail) {
  int idx = blockIdx.x * 256 + threadIdx.x;
  if (idx >= Nn * DIN) return;
  int n = idx >> 5, c = idx & 31;
  unsigned short hi, lo;
  split2(x[idx], hi, lo);
  Aih[(size_t)n * 96 + 64 + c] = hi;
  Ail[(size_t)n * 96 + 64 + c] = lo;
}

// ---------------------------------------------------------------------------
// conv1: h = x @ W_mlp^T + b  (K=32, N=64). Splits x in-kernel.
// ---------------------------------------------------------------------------
__global__ __launch_bounds__(256) void k_conv1(const float* __restrict__ x,
                                               const unsigned short* __restrict__ Wh,
                                               const unsigned short* __restrict__ Wl,
                                               const float* __restrict__ bias,
                                               float* __restrict__ h,
                                               unsigned short* __restrict__ hph,
                                               unsigned short* __restrict__ hpl) {
  int wave = threadIdx.x >> 6, lane = threadIdx.x & 63;
  int quad = lane >> 4;
  int n0w = blockIdx.x * 64 + wave * 16;
  int rowA = n0w + (lane & 15);
  const float4* xp = (const float4*)&x[(size_t)rowA * 32 + quad * 8];
  float4 xa = xp[0], xb = xp[1];
  float xv[8] = {xa.x, xa.y, xa.z, xa.w, xb.x, xb.y, xb.z, xb.w};
  bf16x8 ah, al;
#pragma unroll
  for (int j = 0; j < 8; ++j) {
    unsigned short hi, lo; split2(xv[j], hi, lo);
    ah[j] = (short)hi; al[j] = (short)lo;
  }
  f32x4 acc[4] = {};
#pragma unroll
  for (int nt = 0; nt < 4; ++nt) {
    bf16x8 bh = *(const bf16x8*)&Wh[(nt * 64 + lane) * 8];
    bf16x8 bl = *(const bf16x8*)&Wl[(nt * 64 + lane) * 8];
    acc[nt] = MFMA(ah, bh, acc[nt]);
    acc[nt] = MFMA(ah, bl, acc[nt]);
    acc[nt] = MFMA(al, bh, acc[nt]);
  }
  int col0 = lane & 15;
#pragma unroll
  for (int nt = 0; nt < 4; ++nt) {
    float bv = bias[nt * 16 + col0];
#pragma unroll
    for (int r = 0; r < 4; ++r) {
      int node = n0w + quad * 4 + r;
      float v = acc[nt][r] + bv;
      size_t o = (size_t)node * 64 + nt * 16 + col0;
      h[o] = v;
      unsigned short hi, lo; split2(v, hi, lo);
      hph[o] = hi; hpl[o] = lo;
    }
  }
}

// ---------------------------------------------------------------------------
// lin = h @ W_conv^T + b  (K=64, N=64).  fp32 out.
// ---------------------------------------------------------------------------
__global__ __launch_bounds__(256) void k_lin(const unsigned short* __restrict__ Ah,
                                             const unsigned short* __restrict__ Al,
                                             const unsigned short* __restrict__ Wh,
                                             const unsigned short* __restrict__ Wl,
                                             const float* __restrict__ bias,
                                             float* __restrict__ lin) {
  int wave = threadIdx.x >> 6, lane = threadIdx.x & 63;
  int quad = lane >> 4;
  int n0w = blockIdx.x * 64 + wave * 16;
  int rowA = n0w + (lane & 15);
  f32x4 acc[4] = {};
#pragma unroll
  for (int ks = 0; ks < 2; ++ks) {
    bf16x8 ah = *(const bf16x8*)&Ah[(size_t)rowA * 64 + ks * 32 + quad * 8];
    bf16x8 al = *(const bf16x8*)&Al[(size_t)rowA * 64 + ks * 32 + quad * 8];
#pragma unroll
    for (int nt = 0; nt < 4; ++nt) {
      bf16x8 bh = *(const bf16x8*)&Wh[((nt * 2 + ks) * 64 + lane) * 8];
      bf16x8 bl = *(const bf16x8*)&Wl[((nt * 2 + ks) * 64 + lane) * 8];
      acc[nt] = MFMA(ah, bh, acc[nt]);
      acc[nt] = MFMA(ah, bl, acc[nt]);
      acc[nt] = MFMA(al, bh, acc[nt]);
    }
  }
  int col0 = lane & 15;
#pragma unroll
  for (int nt = 0; nt < 4; ++nt) {
    float bv = bias[nt * 16 + col0];
#pragma unroll
    for (int r = 0; r < 4; ++r) {
      int node = n0w + quad * 4 + r;
      lin[(size_t)node * 64 + nt * 16 + col0] = acc[nt][r] + bv;
    }
  }
}

// ---------------------------------------------------------------------------
// Fused GRU step with LDS-staged weight fragments.
// ---------------------------------------------------------------------------
__global__ __launch_bounds__(256) void k_gru(const unsigned short* __restrict__ Aih,
                                             const unsigned short* __restrict__ Ail,
                                             const unsigned short* __restrict__ Hh,
                                             const unsigned short* __restrict__ Hl,
                                             const unsigned short* __restrict__ Wih_h,
                                             const unsigned short* __restrict__ Wih_l,
                                             const unsigned short* __restrict__ Whh_h,
                                             const unsigned short* __restrict__ Whh_l,
                                             const float* __restrict__ b_ih,
                                             const float* __restrict__ b_hh,
                                             const float* __restrict__ h_old,
                                             float* __restrict__ h_new,
                                             unsigned short* __restrict__ hph,
                                             unsigned short* __restrict__ hpl) {
  __shared__ unsigned short sW[12288];  // hi[12][64][8] | lo[12][64][8]
  int tid = threadIdx.x;
  int wave = tid >> 6, lane = tid & 63;
  int quad = lane >> 4;
  int n0w = blockIdx.x * 64 + wave * 16;
  int rowA = n0w + (lane & 15);
  f32x4 acc[12] = {};   // gi r,z,n; gh r,z folded into [0..7]
  f32x4 accN2[4] = {};  // gh n-gate

  for (int ks = 0; ks < 3; ++ks) {
    __syncthreads();
    for (int i = tid; i < 768; i += 256) {
      int nt = i >> 6, r = i & 63;
      *(bf16x8*)&sW[i * 8] = *(const bf16x8*)&Wih_h[((nt * 3 + ks) * 64 + r) * 8];
      *(bf16x8*)&sW[6144 + i * 8] = *(const bf16x8*)&Wih_l[((nt * 3 + ks) * 64 + r) * 8];
    }
    __syncthreads();
    bf16x8 ah = *(const bf16x8*)&Aih[(size_t)rowA * 96 + ks * 32 + quad * 8];
    bf16x8 al = *(const bf16x8*)&Ail[(size_t)rowA * 96 + ks * 32 + quad * 8];
#pragma unroll
    for (int nt = 0; nt < 12; ++nt) {
      bf16x8 bh = *(const bf16x8*)&sW[(nt * 64 + lane) * 8];
      bf16x8 bl = *(const bf16x8*)&sW[6144 + (nt * 64 + lane) * 8];
      acc[nt] = MFMA(ah, bh, acc[nt]);
      acc[nt] = MFMA(ah, bl, acc[nt]);
      acc[nt] = MFMA(al, bh, acc[nt]);
    }
  }
  for (int ks = 0; ks < 2; ++ks) {
    __syncthreads();
    for (int i = tid; i < 768; i += 256) {
      int nt = i >> 6, r = i & 63;
      *(bf16x8*)&sW[i * 8] = *(const bf16x8*)&Whh_h[((nt * 2 + ks) * 64 + r) * 8];
      *(bf16x8*)&sW[6144 + i * 8] = *(const bf16x8*)&Whh_l[((nt * 2 + ks) * 64 + r) * 8];
    }
    __syncthreads();
    bf16x8 ah = *(const bf16x8*)&Hh[(size_t)rowA * 64 + ks * 32 + quad * 8];
    bf16x8 al = *(const bf16x8*)&Hl[(size_t)rowA * 64 + ks * 32 + quad * 8];
#pragma unroll
    for (int nt = 0; nt < 12; ++nt) {
      bf16x8 bh = *(const bf16x8*)&sW[(nt * 64 + lane) * 8];
      bf16x8 bl = *(const bf16x8*)&sW[6144 + (nt * 64 + lane) * 8];
      if (nt < 8) {
        acc[nt] = MFMA(ah, bh, acc[nt]);
        acc[nt] = MFMA(ah, bl, acc[nt]);
        acc[nt] = MFMA(al, bh, acc[nt]);
      } else {
        accN2[nt - 8] = MFMA(ah, bh, accN2[nt - 8]);
        accN2[nt - 8] = MFMA(ah, bl, accN2[nt - 8]);
        accN2[nt - 8] = MFMA(al, bh, accN2[nt - 8]);
      }
    }
  }

  int col0 = lane & 15;
#pragma unroll
  for (int nt = 0; nt < 4; ++nt) {
    float br  = b_ih[nt * 16 + col0]       + b_hh[nt * 16 + col0];
    float bz  = b_ih[64 + nt * 16 + col0]  + b_hh[64 + nt * 16 + col0];
    float bin = b_ih[128 + nt * 16 + col0];
    float bhn = b_hh[128 + nt * 16 + col0];
#pragma unroll
    for (int r = 0; r < 4; ++r) {
      int node = n0w + quad * 4 + r;
      size_t o = (size_t)node * 64 + nt * 16 + col0;
      float rr = sigf(acc[nt][r] + br);
      float zz = sigf(acc[nt + 4][r] + bz);
      float nn = tanhf(acc[nt + 8][r] + bin + rr * (accN2[nt][r] + bhn));
      float hv = (1.f - zz) * nn + zz * h_old[o];
      h_new[o] = hv;
      unsigned short hi, lo; split2(hv, hi, lo);
      hph[o] = hi; hpl[o] = lo;
    }
  }
}

// ---------------------------------------------------------------------------
// CSR build v3: two-level bucket sort by dst. No global 4B scatter over 4MB.
// ---------------------------------------------------------------------------
// Phase A: 256 blocks x 4096 edges. LDS count -> per-(block,bucket) global
// reservation -> contiguous payload runs (full-line write combining).
__global__ __launch_bounds__(256) void k_bucket(const int* __restrict__ eidx,
                                                int* __restrict__ gcur,     // [NB*16] padded
                                                int* __restrict__ payload) {// [NB*BCAP]
  __shared__ int lcnt[NB];
  __shared__ int lcur[NB];
  int t = threadIdx.x;
  int e0 = blockIdx.x * 4096;
  lcnt[t] = 0;
  __syncthreads();
  int ds[16], ss[16];
#pragma unroll
  for (int i = 0; i < 16; ++i) {
    int e = e0 + i * 256 + t;
    ds[i] = eidx[Ne + e];
    ss[i] = eidx[e];
    atomicAdd(&lcnt[ds[i] >> 8], 1);
  }
  __syncthreads();
  lcur[t] = atomicAdd(&gcur[t * 16], lcnt[t]);  // reserve contiguous run
  __syncthreads();
#pragma unroll
  for (int i = 0; i < 16; ++i) {
    int b = ds[i] >> 8;
    int p = atomicAdd(&lcur[b], 1);
    if (p < BCAP) payload[b * BCAP + p] = (ss[i] << 8) | (ds[i] & 255);
  }
}

// Tiny: scan bucket totals -> bbase; also graphptr + rp[Nn].
__global__ __launch_bounds__(256) void k_bscan(const int* __restrict__ gcur,
                                               int* __restrict__ bbase,
                                               int* __restrict__ rp,
                                               const int* __restrict__ batch,
                                               int* __restrict__ gp) {
  __shared__ int sh[NB];
  int t = threadIdx.x;
  int c = gcur[t * 16];
  sh[t] = c;
  __syncthreads();
  for (int off = 1; off < NB; off <<= 1) {
    int v = (t >= off) ? sh[t - off] : 0;
    __syncthreads();
    sh[t] += v;
    __syncthreads();
  }
  bbase[t] = sh[t] - c;  // exclusive prefix
  if (t == 0) { rp[Nn] = Ne; gp[Bg] = Nn; }
  // graphptr: gp[t] = lower_bound(batch, t)
  int lo = 0, hi = Nn;
  while (lo < hi) {
    int mid = (lo + hi) >> 1;
    if (batch[mid] < t) lo = mid + 1; else hi = mid;
  }
  gp[t] = lo;
}

// Phase B: one block per bucket (256 nodes). LDS hist -> LDS scan -> rp slice,
// then place srcs via LDS cursors. Scatter window ~16KB owned by ONE CU.
__global__ __launch_bounds__(256) void k_placeB(const int* __restrict__ gcur,
                                                const int* __restrict__ bbase,
                                                const int* __restrict__ payload,
                                                int* __restrict__ rp,
                                                int* __restrict__ srcs) {
  __shared__ int hst[NB];
  __shared__ int cur[NB];
  int b = blockIdx.x, t = threadIdx.x;
  int cnt = min(gcur[b * 16], BCAP);
  int base = bbase[b];
  const int* pay = &payload[b * BCAP];
  hst[t] = 0;
  __syncthreads();
  for (int i = t; i < cnt; i += 256) atomicAdd(&hst[pay[i] & 255], 1);
  __syncthreads();
  int c = hst[t];
  cur[t] = c;
  __syncthreads();
  for (int off = 1; off < NB; off <<= 1) {
    int v = (t >= off) ? cur[t - off] : 0;
    __syncthreads();
    cur[t] += v;
    __syncthreads();
  }
  int excl = cur[t] - c;
  rp[b * 256 + t] = base + excl;
  cur[t] = base + excl;
  __syncthreads();
  for (int i = t; i < cnt; i += 256) {
    int pl = pay[i];
    int p = atomicAdd(&cur[pl & 255], 1);
    srcs[p] = pl >> 8;
  }
}

// ---------------------------------------------------------------------------
// CSR aggregate: m[n] = sum over in-edges of lin[src]; writes split planes.
// ---------------------------------------------------------------------------
__global__ void k_aggregate(const int* __restrict__ rp, const int* __restrict__ srcs,
                            const float* __restrict__ lin,
                            unsigned short* __restrict__ Aih,
                            unsigned short* __restrict__ Ail) {
  int t = blockIdx.x * 256 + threadIdx.x;
  int n = t >> 4;
  int q = t & 15;
  int s = rp[n], e = rp[n + 1];
  float4 acc = {0.f, 0.f, 0.f, 0.f};
  for (int i = s; i < e; ++i) {
    int src = srcs[i];
    float4 v = *(const float4*)&lin[(size_t)src * 64 + q * 4];
    acc.x += v.x; acc.y += v.y; acc.z += v.z; acc.w += v.w;
  }
  ushort4 h4, l4;
  split2(acc.x, h4.x, l4.x);
  split2(acc.y, h4.y, l4.y);
  split2(acc.z, h4.z, l4.z);
  split2(acc.w, h4.w, l4.w);
  *(ushort4*)&Aih[(size_t)n * 96 + q * 4] = h4;
  *(ushort4*)&Ail[(size_t)n * 96 + q * 4] = l4;
}

// ---------------------------------------------------------------------------
// Set2Set: LSTM cell (per-graph block).
// ---------------------------------------------------------------------------
__global__ __launch_bounds__(256) void k_lstm(float* __restrict__ q_star,
                                              float* __restrict__ hl,
                                              float* __restrict__ cl,
                                              const float* __restrict__ WihT,
                                              const float* __restrict__ WhhT,
                                              const float* __restrict__ b_ih,
                                              const float* __restrict__ b_hh) {
  int g = blockIdx.x, t = threadIdx.x;
  __shared__ float qs[128], hsh[64], gates[256];
  if (t < 128) qs[t] = q_star[g * 128 + t];
  else if (t < 192) hsh[t - 128] = hl[g * 64 + (t - 128)];
  __syncthreads();
  float acc = b_ih[t] + b_hh[t];
  for (int k = 0; k < 128; ++k) acc = fmaf(WihT[k * 256 + t], qs[k], acc);
  for (int k = 0; k < 64; ++k)  acc = fmaf(WhhT[k * 256 + t], hsh[k], acc);
  gates[t] = acc;
  __syncthreads();
  if (t < 64) {
    float ig = sigf(gates[t]),        fg = sigf(gates[64 + t]);
    float gg = tanhf(gates[128 + t]), og = sigf(gates[192 + t]);
    float c = fg * cl[g * 64 + t] + ig * gg;
    float q = og * tanhf(c);
    cl[g * 64 + t] = c;
    hl[g * 64 + t] = q;
    q_star[g * 128 + t] = q;
  }
}

// ---------------------------------------------------------------------------
// Fused attention: per-graph block.
// ---------------------------------------------------------------------------
constexpr int ACAP = 1024;  // max nodes per graph (dataset max ~330)
__global__ __launch_bounds__(256) void k_attn(const float* __restrict__ h,
                                              const int* __restrict__ gp,
                                              float* __restrict__ q_star) {
  int g = blockIdx.x;
  int t = threadIdx.x;
  int w = t >> 6, lane = t & 63;
  __shared__ float eL[ACAP];
  __shared__ float red[4];
  __shared__ float partial[4][64];
  __shared__ float asum_p[4];
  __shared__ float emax_sh;
  int s = gp[g], e = gp[g + 1];
  int cnt = e - s;

  float4 qv = *(const float4*)&q_star[g * 128 + (lane & 15) * 4];
  for (int i0 = s + w * 4; i0 < e; i0 += 16) {
    int node = i0 + (lane >> 4);
    float p = 0.f;
    if (node < e) {
      float4 o = *(const float4*)&h[(size_t)node * 64 + (lane & 15) * 4];
      p = o.x * qv.x + o.y * qv.y + o.z * qv.z + o.w * qv.w;
    }
    p += __shfl_xor(p, 1); p += __shfl_xor(p, 2);
    p += __shfl_xor(p, 4); p += __shfl_xor(p, 8);
    if (node < e && (lane & 15) == 0) eL[node - s] = p;
  }
  __syncthreads();

  float m = -INFINITY;
  for (int i = t; i < cnt; i += 256) m = fmaxf(m, eL[i]);
#pragma unroll
  for (int o = 32; o >= 1; o >>= 1) m = fmaxf(m, __shfl_xor(m, o));
  if (lane == 0) red[w] = m;
  __syncthreads();
  if (t == 0) {
    float mm = fmaxf(fmaxf(red[0], red[1]), fmaxf(red[2], red[3]));
    emax_sh = isfinite(mm) ? mm : 0.f;
  }
  __syncthreads();
  float emax = emax_sh;

  float acc = 0.f, asum = 0.f;
  for (int i = s + w; i < e; i += 4) {
    float a = expf(eL[i - s] - emax);
    asum += a;
    acc = fmaf(a, h[(size_t)i * 64 + lane], acc);
  }
  partial[w][lane] = acc;
  if (lane == 0) asum_p[w] = asum;
  __syncthreads();
  if (t < 64) {
    float r  = partial[0][t] + partial[1][t] + partial[2][t] + partial[3][t];
    float as = asum_p[0] + asum_p[1] + asum_p[2] + asum_p[3];
    q_star[g * 128 + 64 + t] = (cnt > 0) ? r / fmaxf(as, 1e-16f) : 0.f;
  }
}

// ---------------------------------------------------------------------------
// Head
// ---------------------------------------------------------------------------
__global__ __launch_bounds__(64) void k_head(const float* __restrict__ q_star,
                                             const float* __restrict__ W1T,
                                             const float* __restrict__ b1,
                                             const float* __restrict__ W2,
                                             const float* __restrict__ b2,
                                             float* __restrict__ outp) {
  int g = blockIdx.x;
  int lane = threadIdx.x;
  __shared__ float qsh[128];
  __shared__ float hsh[64];
  __shared__ float l4[4];
  qsh[lane] = q_star[g * 128 + lane];
  qsh[64 + lane] = q_star[g * 128 + 64 + lane];
  __syncthreads();
  float acc = b1[lane];
  for (int k = 0; k < 128; ++k) acc = fmaf(W1T[k * 64 + lane], qsh[k], acc);
  hsh[lane] = fmaxf(acc, 0.f);
  __syncthreads();
  if (lane < 4) {
    float lg = b2[lane];
    for (int d = 0; d < 64; ++d) lg = fmaf(W2[lane * 64 + d], hsh[d], lg);
    l4[lane] = lg;
  }
  __syncthreads();
  if (lane < 4) {
    float m = fmaxf(fmaxf(l4[0], l4[1]), fmaxf(l4[2], l4[3]));
    float ssum = expf(l4[0] - m) + expf(l4[1] - m) + expf(l4[2] - m) + expf(l4[3] - m);
    outp[g * 4 + lane] = l4[lane] - m - logf(ssum);
  }
}

// ---------------------------------------------------------------------------
extern "C" void kernel_launch(void* const* d_in, const int* in_sizes, int n_in,
                              void* d_out, int out_size, void* d_ws, size_t ws_size,
                              hipStream_t stream) {
  const float* x        = (const float*)d_in[0];
  const int*   eidx     = (const int*)d_in[1];
  const int*   batch    = (const int*)d_in[2];
  const float* W_mlp    = (const float*)d_in[3];
  const float* b_mlp    = (const float*)d_in[4];
  const float* W_conv   = (const float*)d_in[5];
  const float* b_conv   = (const float*)d_in[6];
  const float* gW_ih    = (const float*)d_in[7];
  const float* gW_hh    = (const float*)d_in[8];
  const float* gb_ih    = (const float*)d_in[9];
  const float* gb_hh    = (const float*)d_in[10];
  const float* lW_ih    = (const float*)d_in[11];
  const float* lW_hh    = (const float*)d_in[12];
  const float* lb_ih    = (const float*)d_in[13];
  const float* lb_hh    = (const float*)d_in[14];
  const float* W1       = (const float*)d_in[15];
  const float* b1       = (const float*)d_in[16];
  const float* W2       = (const float*)d_in[17];
  const float* b2       = (const float*)d_in[18];
  float* outp = (float*)d_out;

  // ---- workspace layout ----
  char* ws = (char*)d_ws;
  size_t off = 0;
  auto alloc = [&](size_t bytes) { size_t r = off; off = (off + bytes + 255) & ~(size_t)255; return r; };
  float* hA  = (float*)(ws + alloc((size_t)Nn * 64 * 4));
  float* hB  = (float*)(ws + alloc((size_t)Nn * 64 * 4));
  unsigned short* hpAh = (unsigned short*)(ws + alloc((size_t)Nn * 64 * 2));
  unsigned short* hpAl = (unsigned short*)(ws + alloc((size_t)Nn * 64 * 2));
  unsigned short* hpBh = (unsigned short*)(ws + alloc((size_t)Nn * 64 * 2));
  unsigned short* hpBl = (unsigned short*)(ws + alloc((size_t)Nn * 64 * 2));
  unsigned short* Aih  = (unsigned short*)(ws + alloc((size_t)Nn * 96 * 2));
  unsigned short* Ail  = (unsigned short*)(ws + alloc((size_t)Nn * 96 * 2));
  float* lin   = (float*)(ws + alloc((size_t)Nn * 64 * 4));
  int*   rp    = (int*)(ws + alloc((size_t)(Nn + 1) * 4));
  int*   srcs  = (int*)(ws + alloc((size_t)Ne * 4));
  int*   gcur  = (int*)(ws + alloc((size_t)NB * 16 * 4));
  int*   bbase = (int*)(ws + alloc((size_t)NB * 4));
  int*   payload = (int*)(ws + alloc((size_t)NB * BCAP * 4));
  int*   gp    = (int*)(ws + alloc((size_t)(Bg + 1) * 4));
  float* WihT  = (float*)(ws + alloc((size_t)128 * 256 * 4));
  float* WhhT  = (float*)(ws + alloc((size_t)64 * 256 * 4));
  float* W1T   = (float*)(ws + alloc((size_t)128 * 64 * 4));
  unsigned short* mlp_h = (unsigned short*)(ws + alloc(2048 * 2));
  unsigned short* mlp_l = (unsigned short*)(ws + alloc(2048 * 2));
  unsigned short* cv_h  = (unsigned short*)(ws + alloc(4096 * 2));
  unsigned short* cv_l  = (unsigned short*)(ws + alloc(4096 * 2));
  unsigned short* ih_h  = (unsigned short*)(ws + alloc(18432 * 2));
  unsigned short* ih_l  = (unsigned short*)(ws + alloc(18432 * 2));
  unsigned short* hh_h  = (unsigned short*)(ws + alloc(12288 * 2));
  unsigned short* hh_l  = (unsigned short*)(ws + alloc(12288 * 2));
  float* s2s   = (float*)(ws + alloc((size_t)Bg * (128 + 64 + 64) * 4));
  float* q_star = s2s;
  float* hl     = s2s + Bg * 128;
  float* cl     = s2s + Bg * 128 + Bg * 64;
  (void)in_sizes; (void)n_in; (void)out_size; (void)ws_size;

  hipMemsetAsync(gcur, 0, (size_t)NB * 16 * 4, stream);
  hipMemsetAsync(s2s, 0, (size_t)Bg * 256 * 4, stream);

  // CSR build v3 (bucket sort) + prep
  k_bucket<<<Ne / 4096, 256, 0, stream>>>(eidx, gcur, payload);
  k_bscan<<<1, 256, 0, stream>>>(gcur, bbase, rp, batch, gp);
  k_placeB<<<NB, 256, 0, stream>>>(gcur, bbase, payload, rp, srcs);
  k_prepw<<<368, 256, 0, stream>>>(W_mlp, W_conv, gW_ih, gW_hh, lW_ih, lW_hh, W1,
                                   mlp_h, mlp_l, cv_h, cv_l, ih_h, ih_l, hh_h, hh_l,
                                   WihT, WhhT, W1T);
  k_prepx<<<Nn * DIN / 256, 256, 0, stream>>>(x, Aih, Ail);

  // conv1
  k_conv1<<<Nn / 64, 256, 0, stream>>>(x, mlp_h, mlp_l, b_mlp, hA, hpAh, hpAl);

  float* h = hA; float* h2 = hB;
  unsigned short *cph = hpAh, *cpl = hpAl, *nph = hpBh, *npl = hpBl;
  for (int step = 0; step < 2; ++step) {
    k_lin<<<Nn / 64, 256, 0, stream>>>(cph, cpl, cv_h, cv_l, b_conv, lin);
    k_aggregate<<<Nn * 16 / 256, 256, 0, stream>>>(rp, srcs, lin, Aih, Ail);
    k_gru<<<Nn / 64, 256, 0, stream>>>(Aih, Ail, cph, cpl, ih_h, ih_l, hh_h, hh_l,
                                       gb_ih, gb_hh, h, h2, nph, npl);
    float* tf = h; h = h2; h2 = tf;
    unsigned short* tu;
    tu = cph; cph = nph; nph = tu;
    tu = cpl; cpl = npl; npl = tu;
  }

  for (int it = 0; it < 3; ++it) {
    k_lstm<<<Bg, 256, 0, stream>>>(q_star, hl, cl, WihT, WhhT, lb_ih, lb_hh);
    k_attn<<<Bg, 256, 0, stream>>>(h, gp, q_star);
  }
  k_head<<<Bg, 64, 0, stream>>>(q_star, W1T, b1, W2, b2, outp);
}

// Round 8
// 382.440 us; speedup vs baseline: 1.4766x; 1.1242x over previous
//
#include <hip/hip_runtime.h>
#include <math.h>

constexpr int Nn  = 65536;    // nodes
constexpr int Ne  = 1048576;  // edges
constexpr int Bg  = 256;      // graphs
constexpr int DIN = 32;
constexpr int D   = 64;

constexpr int NB   = 256;     // dst buckets (dst>>8)
constexpr int BCAP = 6144;    // bucket stream capacity (mean 4096, +36 sigma)

typedef __attribute__((ext_vector_type(8))) short bf16x8;
typedef __attribute__((ext_vector_type(4))) float f32x4;

__device__ __forceinline__ float sigf(float x) { return 1.0f / (1.0f + expf(-x)); }

// ---- bf16 split helpers (RNE) ----
__device__ __forceinline__ unsigned short bf16_rne(float f) {
  unsigned u = __float_as_uint(f);
  unsigned r = u + 0x7FFFu + ((u >> 16) & 1u);
  return (unsigned short)(r >> 16);
}
__device__ __forceinline__ float bf16_tof(unsigned short h) {
  return __uint_as_float(((unsigned)h) << 16);
}
__device__ __forceinline__ void split2(float f, unsigned short& hi, unsigned short& lo) {
  hi = bf16_rne(f);
  lo = bf16_rne(f - bf16_tof(hi));
}
// reconstruct h from planes
__device__ __forceinline__ float recon(unsigned short hi, unsigned short lo) {
  return bf16_tof(hi) + bf16_tof(lo);
}

#define MFMA(a, b, c) __builtin_amdgcn_mfma_f32_16x16x32_bf16(a, b, c, 0, 0, 0)

// ---------------------------------------------------------------------------
// Prep: weight fragment packing (idx<36864) + transposes + gp + rp[Nn].
// ---------------------------------------------------------------------------
__global__ void k_prepw(const float* __restrict__ W_mlp, const float* __restrict__ W_conv,
                        const float* __restrict__ gWih, const float* __restrict__ gWhh,
                        const float* __restrict__ lW_ih, const float* __restrict__ lW_hh,
                        const float* __restrict__ W1,
                        unsigned short* __restrict__ mlp_h, unsigned short* __restrict__ mlp_l,
                        unsigned short* __restrict__ cv_h,  unsigned short* __restrict__ cv_l,
                        unsigned short* __restrict__ ih_h,  unsigned short* __restrict__ ih_l,
                        unsigned short* __restrict__ hh_h,  unsigned short* __restrict__ hh_l,
                        float* __restrict__ WihT, float* __restrict__ WhhT,
                        float* __restrict__ W1T,
                        const int* __restrict__ batch, int* __restrict__ gp,
                        int* __restrict__ rp) {
  int idx = blockIdx.x * 256 + threadIdx.x;
  if (idx < 36864) {
    const float* W; int K, KS; unsigned short *oh, *ol; int lp = idx;
    if (idx < 2048)       { W = W_mlp;  K = 32; KS = 1; oh = mlp_h; ol = mlp_l; }
    else if (idx < 6144)  { W = W_conv; K = 64; KS = 2; oh = cv_h;  ol = cv_l;  lp -= 2048; }
    else if (idx < 24576) { W = gWih;   K = 96; KS = 3; oh = ih_h;  ol = ih_l;  lp -= 6144; }
    else                  { W = gWhh;   K = 64; KS = 2; oh = hh_h;  ol = hh_l;  lp -= 24576; }
    int j = lp & 7, lane = (lp >> 3) & 63, q = lp >> 9;
    int ks = q % KS, nt = q / KS;
    int n = nt * 16 + (lane & 15);
    int k = ks * 32 + (lane >> 4) * 8 + j;
    unsigned short hi, lo;
    split2(W[n * K + k], hi, lo);
    oh[lp] = hi; ol[lp] = lo;
    return;
  }
  int t = idx - 36864;
  if (t < 32768) {                 // lstm W_ih [256][128] -> WihT [128][256]
    int row = t / 128, k = t % 128;
    WihT[k * 256 + row] = lW_ih[t];
  } else if (t < 49152) {          // lstm W_hh [256][64] -> WhhT [64][256]
    int j = t - 32768;
    int row = j / 64, k = j % 64;
    WhhT[k * 256 + row] = lW_hh[j];
  } else if (t < 57344) {          // W1 [64][128] -> W1T [128][64]
    int j = t - 49152;
    int row = j / 128, k = j % 128;
    W1T[k * 64 + row] = W1[j];
  } else if (t < 57344 + Bg + 1) { // graphptr + rp[Nn]
    int g = t - 57344;
    if (g == 0) rp[Nn] = Ne;
    int lo = 0, hi = Nn;
    while (lo < hi) {
      int mid = (lo + hi) >> 1;
      if (batch[mid] < g) lo = mid + 1; else hi = mid;
    }
    gp[g] = lo;
  }
}

// ---------------------------------------------------------------------------
// conv1: h = x @ W_mlp^T + b  (K=32, N=64). Splits x in-kernel; also fills
// inp96 x-columns (64..95) from its x fragments.  h stored as planes only.
// ---------------------------------------------------------------------------
__global__ __launch_bounds__(256) void k_conv1(const float* __restrict__ x,
                                               const unsigned short* __restrict__ Wh,
                                               const unsigned short* __restrict__ Wl,
                                               const float* __restrict__ bias,
                                               unsigned short* __restrict__ hph,
                                               unsigned short* __restrict__ hpl,
                                               unsigned short* __restrict__ Aih,
                                               unsigned short* __restrict__ Ail) {
  int wave = threadIdx.x >> 6, lane = threadIdx.x & 63;
  int quad = lane >> 4;
  int n0w = blockIdx.x * 64 + wave * 16;
  int rowA = n0w + (lane & 15);
  const float4* xp = (const float4*)&x[(size_t)rowA * 32 + quad * 8];
  float4 xa = xp[0], xb = xp[1];
  float xv[8] = {xa.x, xa.y, xa.z, xa.w, xb.x, xb.y, xb.z, xb.w};
  bf16x8 ah, al;
#pragma unroll
  for (int j = 0; j < 8; ++j) {
    unsigned short hi, lo; split2(xv[j], hi, lo);
    ah[j] = (short)hi; al[j] = (short)lo;
  }
  // x-columns of inp96 (cols 64..95): 16B plane stores straight from fragments
  *(bf16x8*)&Aih[(size_t)rowA * 96 + 64 + quad * 8] = ah;
  *(bf16x8*)&Ail[(size_t)rowA * 96 + 64 + quad * 8] = al;

  f32x4 acc[4] = {};
#pragma unroll
  for (int nt = 0; nt < 4; ++nt) {
    bf16x8 bh = *(const bf16x8*)&Wh[(nt * 64 + lane) * 8];
    bf16x8 bl = *(const bf16x8*)&Wl[(nt * 64 + lane) * 8];
    acc[nt] = MFMA(ah, bh, acc[nt]);
    acc[nt] = MFMA(ah, bl, acc[nt]);
    acc[nt] = MFMA(al, bh, acc[nt]);
  }
  int col0 = lane & 15;
#pragma unroll
  for (int nt = 0; nt < 4; ++nt) {
    float bv = bias[nt * 16 + col0];
#pragma unroll
    for (int r = 0; r < 4; ++r) {
      int node = n0w + quad * 4 + r;
      float v = acc[nt][r] + bv;
      size_t o = (size_t)node * 64 + nt * 16 + col0;
      unsigned short hi, lo; split2(v, hi, lo);
      hph[o] = hi; hpl[o] = lo;
    }
  }
}

// ---------------------------------------------------------------------------
// lin = h @ W_conv^T + b  (K=64, N=64).  fp32 out (feeds gather).
// ---------------------------------------------------------------------------
__global__ __launch_bounds__(256) void k_lin(const unsigned short* __restrict__ Ah,
                                             const unsigned short* __restrict__ Al,
                                             const unsigned short* __restrict__ Wh,
                                             const unsigned short* __restrict__ Wl,
                                             const float* __restrict__ bias,
                                             float* __restrict__ lin) {
  int wave = threadIdx.x >> 6, lane = threadIdx.x & 63;
  int quad = lane >> 4;
  int n0w = blockIdx.x * 64 + wave * 16;
  int rowA = n0w + (lane & 15);
  f32x4 acc[4] = {};
#pragma unroll
  for (int ks = 0; ks < 2; ++ks) {
    bf16x8 ah = *(const bf16x8*)&Ah[(size_t)rowA * 64 + ks * 32 + quad * 8];
    bf16x8 al = *(const bf16x8*)&Al[(size_t)rowA * 64 + ks * 32 + quad * 8];
#pragma unroll
    for (int nt = 0; nt < 4; ++nt) {
      bf16x8 bh = *(const bf16x8*)&Wh[((nt * 2 + ks) * 64 + lane) * 8];
      bf16x8 bl = *(const bf16x8*)&Wl[((nt * 2 + ks) * 64 + lane) * 8];
      acc[nt] = MFMA(ah, bh, acc[nt]);
      acc[nt] = MFMA(ah, bl, acc[nt]);
      acc[nt] = MFMA(al, bh, acc[nt]);
    }
  }
  int col0 = lane & 15;
#pragma unroll
  for (int nt = 0; nt < 4; ++nt) {
    float bv = bias[nt * 16 + col0];
#pragma unroll
    for (int r = 0; r < 4; ++r) {
      int node = n0w + quad * 4 + r;
      lin[(size_t)node * 64 + nt * 16 + col0] = acc[nt][r] + bv;
    }
  }
}

// ---------------------------------------------------------------------------
// Fused GRU step with LDS-staged weight fragments.  h stored as planes only:
// h_old read from the previous planes; h_new written as planes.
// ---------------------------------------------------------------------------
__global__ __launch_bounds__(256) void k_gru(const unsigned short* __restrict__ Aih,
                                             const unsigned short* __restrict__ Ail,
                                             const unsigned short* __restrict__ Hh,
                                             const unsigned short* __restrict__ Hl,
                                             const unsigned short* __restrict__ Wih_h,
                                             const unsigned short* __restrict__ Wih_l,
                                             const unsigned short* __restrict__ Whh_h,
                                             const unsigned short* __restrict__ Whh_l,
                                             const float* __restrict__ b_ih,
                                             const float* __restrict__ b_hh,
                                             unsigned short* __restrict__ nph,
                                             unsigned short* __restrict__ npl) {
  __shared__ unsigned short sW[12288];  // hi[12][64][8] | lo[12][64][8]
  int tid = threadIdx.x;
  int wave = tid >> 6, lane = tid & 63;
  int quad = lane >> 4;
  int n0w = blockIdx.x * 64 + wave * 16;
  int rowA = n0w + (lane & 15);
  f32x4 acc[12] = {};   // gi r,z,n; gh r,z folded into [0..7]
  f32x4 accN2[4] = {};  // gh n-gate

  for (int ks = 0; ks < 3; ++ks) {
    __syncthreads();
    for (int i = tid; i < 768; i += 256) {
      int nt = i >> 6, r = i & 63;
      *(bf16x8*)&sW[i * 8] = *(const bf16x8*)&Wih_h[((nt * 3 + ks) * 64 + r) * 8];
      *(bf16x8*)&sW[6144 + i * 8] = *(const bf16x8*)&Wih_l[((nt * 3 + ks) * 64 + r) * 8];
    }
    __syncthreads();
    bf16x8 ah = *(const bf16x8*)&Aih[(size_t)rowA * 96 + ks * 32 + quad * 8];
    bf16x8 al = *(const bf16x8*)&Ail[(size_t)rowA * 96 + ks * 32 + quad * 8];
#pragma unroll
    for (int nt = 0; nt < 12; ++nt) {
      bf16x8 bh = *(const bf16x8*)&sW[(nt * 64 + lane) * 8];
      bf16x8 bl = *(const bf16x8*)&sW[6144 + (nt * 64 + lane) * 8];
      acc[nt] = MFMA(ah, bh, acc[nt]);
      acc[nt] = MFMA(ah, bl, acc[nt]);
      acc[nt] = MFMA(al, bh, acc[nt]);
    }
  }
  for (int ks = 0; ks < 2; ++ks) {
    __syncthreads();
    for (int i = tid; i < 768; i += 256) {
      int nt = i >> 6, r = i & 63;
      *(bf16x8*)&sW[i * 8] = *(const bf16x8*)&Whh_h[((nt * 2 + ks) * 64 + r) * 8];
      *(bf16x8*)&sW[6144 + i * 8] = *(const bf16x8*)&Whh_l[((nt * 2 + ks) * 64 + r) * 8];
    }
    __syncthreads();
    bf16x8 ah = *(const bf16x8*)&Hh[(size_t)rowA * 64 + ks * 32 + quad * 8];
    bf16x8 al = *(const bf16x8*)&Hl[(size_t)rowA * 64 + ks * 32 + quad * 8];
#pragma unroll
    for (int nt = 0; nt < 12; ++nt) {
      bf16x8 bh = *(const bf16x8*)&sW[(nt * 64 + lane) * 8];
      bf16x8 bl = *(const bf16x8*)&sW[6144 + (nt * 64 + lane) * 8];
      if (nt < 8) {
        acc[nt] = MFMA(ah, bh, acc[nt]);
        acc[nt] = MFMA(ah, bl, acc[nt]);
        acc[nt] = MFMA(al, bh, acc[nt]);
      } else {
        accN2[nt - 8] = MFMA(ah, bh, accN2[nt - 8]);
        accN2[nt - 8] = MFMA(ah, bl, accN2[nt - 8]);
        accN2[nt - 8] = MFMA(al, bh, accN2[nt - 8]);
      }
    }
  }

  int col0 = lane & 15;
#pragma unroll
  for (int nt = 0; nt < 4; ++nt) {
    float br  = b_ih[nt * 16 + col0]       + b_hh[nt * 16 + col0];
    float bz  = b_ih[64 + nt * 16 + col0]  + b_hh[64 + nt * 16 + col0];
    float bin = b_ih[128 + nt * 16 + col0];
    float bhn = b_hh[128 + nt * 16 + col0];
#pragma unroll
    for (int r = 0; r < 4; ++r) {
      int node = n0w + quad * 4 + r;
      size_t o = (size_t)node * 64 + nt * 16 + col0;
      float rr = sigf(acc[nt][r] + br);
      float zz = sigf(acc[nt + 4][r] + bz);
      float nn = tanhf(acc[nt + 8][r] + bin + rr * (accN2[nt][r] + bhn));
      float h_old = recon(Hh[o], Hl[o]);
      float hv = (1.f - zz) * nn + zz * h_old;
      unsigned short hi, lo; split2(hv, hi, lo);
      nph[o] = hi; npl[o] = lo;
    }
  }
}

// ---------------------------------------------------------------------------
// CSR build v3: two-level bucket sort by dst.
// ---------------------------------------------------------------------------
__global__ __launch_bounds__(256) void k_bucket(const int* __restrict__ eidx,
                                                int* __restrict__ gcur,     // [NB*16]
                                                int* __restrict__ payload) {// [NB*BCAP]
  __shared__ int lcnt[NB];
  __shared__ int lcur[NB];
  int t = threadIdx.x;
  int e0 = blockIdx.x * 4096;
  lcnt[t] = 0;
  __syncthreads();
  int ds[16], ss[16];
#pragma unroll
  for (int i = 0; i < 16; ++i) {
    int e = e0 + i * 256 + t;
    ds[i] = eidx[Ne + e];
    ss[i] = eidx[e];
    atomicAdd(&lcnt[ds[i] >> 8], 1);
  }
  __syncthreads();
  lcur[t] = atomicAdd(&gcur[t * 16], lcnt[t]);  // reserve contiguous run
  __syncthreads();
#pragma unroll
  for (int i = 0; i < 16; ++i) {
    int b = ds[i] >> 8;
    int p = atomicAdd(&lcur[b], 1);
    if (p < BCAP) payload[b * BCAP + p] = (ss[i] << 8) | (ds[i] & 255);
  }
}

// One block per bucket: inline scan of gcur -> base, LDS hist -> rp slice,
// place srcs via LDS cursors (scatter window owned by one CU).
__global__ __launch_bounds__(256) void k_placeB(const int* __restrict__ gcur,
                                                const int* __restrict__ payload,
                                                int* __restrict__ rp,
                                                int* __restrict__ srcs) {
  __shared__ int sAll[NB];
  __shared__ int hst[NB];
  __shared__ int cur[NB];
  int b = blockIdx.x, t = threadIdx.x;
  sAll[t] = gcur[t * 16];
  hst[t] = 0;
  __syncthreads();
  int cnt = min(sAll[b], BCAP);
  // inclusive scan of sAll
  for (int off = 1; off < NB; off <<= 1) {
    int v = (t >= off) ? sAll[t - off] : 0;
    __syncthreads();
    sAll[t] += v;
    __syncthreads();
  }
  int base = sAll[b] - min(gcur[b * 16], BCAP) - 0;  // careful below
  base = sAll[b] - gcur[b * 16];                     // exclusive prefix (true counts)
  const int* pay = &payload[b * BCAP];
  for (int i = t; i < cnt; i += 256) atomicAdd(&hst[pay[i] & 255], 1);
  __syncthreads();
  int c = hst[t];
  cur[t] = c;
  __syncthreads();
  for (int off = 1; off < NB; off <<= 1) {
    int v = (t >= off) ? cur[t - off] : 0;
    __syncthreads();
    cur[t] += v;
    __syncthreads();
  }
  int excl = cur[t] - c;
  rp[b * 256 + t] = base + excl;
  cur[t] = base + excl;
  __syncthreads();
  for (int i = t; i < cnt; i += 256) {
    int pl = pay[i];
    int p = atomicAdd(&cur[pl & 255], 1);
    srcs[p] = pl >> 8;
  }
}

// ---------------------------------------------------------------------------
// CSR aggregate: m[n] = sum over in-edges of lin[src]; writes split planes.
// ---------------------------------------------------------------------------
__global__ void k_aggregate(const int* __restrict__ rp, const int* __restrict__ srcs,
                            const float* __restrict__ lin,
                            unsigned short* __restrict__ Aih,
                            unsigned short* __restrict__ Ail) {
  int t = blockIdx.x * 256 + threadIdx.x;
  int n = t >> 4;
  int q = t & 15;
  int s = rp[n], e = rp[n + 1];
  float4 acc = {0.f, 0.f, 0.f, 0.f};
  for (int i = s; i < e; ++i) {
    int src = srcs[i];
    float4 v = *(const float4*)&lin[(size_t)src * 64 + q * 4];
    acc.x += v.x; acc.y += v.y; acc.z += v.z; acc.w += v.w;
  }
  ushort4 h4, l4;
  split2(acc.x, h4.x, l4.x);
  split2(acc.y, h4.y, l4.y);
  split2(acc.z, h4.z, l4.z);
  split2(acc.w, h4.w, l4.w);
  *(ushort4*)&Aih[(size_t)n * 96 + q * 4] = h4;
  *(ushort4*)&Ail[(size_t)n * 96 + q * 4] = l4;
}

// ---------------------------------------------------------------------------
// Fused Set2Set iteration: LSTM cell + attention (+ optional head).
// One block per graph.  h read from planes.
// ---------------------------------------------------------------------------
constexpr int ACAP = 1024;  // max nodes per graph (dataset max ~330)
__global__ __launch_bounds__(256) void k_s2s(const unsigned short* __restrict__ hph,
                                             const unsigned short* __restrict__ hpl,
                                             const int* __restrict__ gp,
                                             float* __restrict__ q_star,
                                             float* __restrict__ hl,
                                             float* __restrict__ cl,
                                             const float* __restrict__ WihT,
                                             const float* __restrict__ WhhT,
                                             const float* __restrict__ b_ih,
                                             const float* __restrict__ b_hh,
                                             const float* __restrict__ W1T,
                                             const float* __restrict__ b1,
                                             const float* __restrict__ W2,
                                             const float* __restrict__ b2,
                                             float* __restrict__ outp,
                                             int first, int do_head) {
  int g = blockIdx.x;
  int t = threadIdx.x;
  int w = t >> 6, lane = t & 63;
  __shared__ float qs[128], hsh[64], gates[256];
  __shared__ float qsh[64], rsh[64];
  __shared__ float eL[ACAP];
  __shared__ float red[4];
  __shared__ float partial[4][64];
  __shared__ float asum_p[4];
  __shared__ float emax_sh;
  __shared__ float l4[4];

  // ---- LSTM cell ----
  if (t < 128) qs[t] = first ? 0.f : q_star[g * 128 + t];
  else if (t < 192) hsh[t - 128] = first ? 0.f : hl[g * 64 + (t - 128)];
  __syncthreads();
  {
    float acc = b_ih[t] + b_hh[t];
    for (int k = 0; k < 128; ++k) acc = fmaf(WihT[k * 256 + t], qs[k], acc);
    for (int k = 0; k < 64; ++k)  acc = fmaf(WhhT[k * 256 + t], hsh[k], acc);
    gates[t] = acc;
  }
  __syncthreads();
  if (t < 64) {
    float ig = sigf(gates[t]),        fg = sigf(gates[64 + t]);
    float gg = tanhf(gates[128 + t]), og = sigf(gates[192 + t]);
    float c_old = first ? 0.f : cl[g * 64 + t];
    float c = fg * c_old + ig * gg;
    float q = og * tanhf(c);
    cl[g * 64 + t] = c;
    hl[g * 64 + t] = q;
    q_star[g * 128 + t] = q;
    qsh[t] = q;
  }
  __syncthreads();

  int s = gp[g], e = gp[g + 1];
  int cnt = e - s;

  // ---- attention phase A: e_i = h[i].q ----
  int c4 = (lane & 15) * 4;
  float4 qv = {qsh[c4], qsh[c4 + 1], qsh[c4 + 2], qsh[c4 + 3]};
  for (int i0 = s + w * 4; i0 < e; i0 += 16) {
    int node = i0 + (lane >> 4);
    float p = 0.f;
    if (node < e) {
      ushort4 h4 = *(const ushort4*)&hph[(size_t)node * 64 + c4];
      ushort4 l4v = *(const ushort4*)&hpl[(size_t)node * 64 + c4];
      p = recon(h4.x, l4v.x) * qv.x + recon(h4.y, l4v.y) * qv.y +
          recon(h4.z, l4v.z) * qv.z + recon(h4.w, l4v.w) * qv.w;
    }
    p += __shfl_xor(p, 1); p += __shfl_xor(p, 2);
    p += __shfl_xor(p, 4); p += __shfl_xor(p, 8);
    if (node < e && (lane & 15) == 0) eL[node - s] = p;
  }
  __syncthreads();

  // ---- phase B: segment max ----
  float m = -INFINITY;
  for (int i = t; i < cnt; i += 256) m = fmaxf(m, eL[i]);
#pragma unroll
  for (int o = 32; o >= 1; o >>= 1) m = fmaxf(m, __shfl_xor(m, o));
  if (lane == 0) red[w] = m;
  __syncthreads();
  if (t == 0) {
    float mm = fmaxf(fmaxf(red[0], red[1]), fmaxf(red[2], red[3]));
    emax_sh = isfinite(mm) ? mm : 0.f;
  }
  __syncthreads();
  float emax = emax_sh;

  // ---- phase C: softmax-weighted feature sum ----
  float acc = 0.f, asum = 0.f;
  for (int i = s + w; i < e; i += 4) {
    float a = expf(eL[i - s] - emax);
    asum += a;
    float hv = recon(hph[(size_t)i * 64 + lane], hpl[(size_t)i * 64 + lane]);
    acc = fmaf(a, hv, acc);
  }
  partial[w][lane] = acc;
  if (lane == 0) asum_p[w] = asum;
  __syncthreads();
  if (t < 64) {
    float r  = partial[0][t] + partial[1][t] + partial[2][t] + partial[3][t];
    float as = asum_p[0] + asum_p[1] + asum_p[2] + asum_p[3];
    float rv = (cnt > 0) ? r / fmaxf(as, 1e-16f) : 0.f;
    q_star[g * 128 + 64 + t] = rv;
    rsh[t] = rv;
  }
  if (!do_head) return;
  __syncthreads();

  // ---- head: hid = relu(q_star @ W1^T + b1); logits; log_softmax ----
  if (t < 64) {
    float a1 = b1[t];
    for (int k = 0; k < 64; ++k)  a1 = fmaf(W1T[k * 64 + t], qsh[k], a1);
    for (int k = 64; k < 128; ++k) a1 = fmaf(W1T[k * 64 + t], rsh[k - 64], a1);
    hsh[t] = fmaxf(a1, 0.f);
  }
  __syncthreads();
  if (t < 4) {
    float lg = b2[t];
    for (int d = 0; d < 64; ++d) lg = fmaf(W2[t * 64 + d], hsh[d], lg);
    l4[t] = lg;
  }
  __syncthreads();
  if (t < 4) {
    float mx = fmaxf(fmaxf(l4[0], l4[1]), fmaxf(l4[2], l4[3]));
    float ssum = expf(l4[0] - mx) + expf(l4[1] - mx) + expf(l4[2] - mx) + expf(l4[3] - mx);
    outp[g * 4 + t] = l4[t] - mx - logf(ssum);
  }
}

// ---------------------------------------------------------------------------
extern "C" void kernel_launch(void* const* d_in, const int* in_sizes, int n_in,
                              void* d_out, int out_size, void* d_ws, size_t ws_size,
                              hipStream_t stream) {
  const float* x        = (const float*)d_in[0];
  const int*   eidx     = (const int*)d_in[1];
  const int*   batch    = (const int*)d_in[2];
  const float* W_mlp    = (const float*)d_in[3];
  const float* b_mlp    = (const float*)d_in[4];
  const float* W_conv   = (const float*)d_in[5];
  const float* b_conv   = (const float*)d_in[6];
  const float* gW_ih    = (const float*)d_in[7];
  const float* gW_hh    = (const float*)d_in[8];
  const float* gb_ih    = (const float*)d_in[9];
  const float* gb_hh    = (const float*)d_in[10];
  const float* lW_ih    = (const float*)d_in[11];
  const float* lW_hh    = (const float*)d_in[12];
  const float* lb_ih    = (const float*)d_in[13];
  const float* lb_hh    = (const float*)d_in[14];
  const float* W1       = (const float*)d_in[15];
  const float* b1       = (const float*)d_in[16];
  const float* W2       = (const float*)d_in[17];
  const float* b2       = (const float*)d_in[18];
  float* outp = (float*)d_out;

  // ---- workspace layout ----
  char* ws = (char*)d_ws;
  size_t off = 0;
  auto alloc = [&](size_t bytes) { size_t r = off; off = (off + bytes + 255) & ~(size_t)255; return r; };
  unsigned short* hpAh = (unsigned short*)(ws + alloc((size_t)Nn * 64 * 2));
  unsigned short* hpAl = (unsigned short*)(ws + alloc((size_t)Nn * 64 * 2));
  unsigned short* hpBh = (unsigned short*)(ws + alloc((size_t)Nn * 64 * 2));
  unsigned short* hpBl = (unsigned short*)(ws + alloc((size_t)Nn * 64 * 2));
  unsigned short* Aih  = (unsigned short*)(ws + alloc((size_t)Nn * 96 * 2));
  unsigned short* Ail  = (unsigned short*)(ws + alloc((size_t)Nn * 96 * 2));
  float* lin   = (float*)(ws + alloc((size_t)Nn * 64 * 4));
  int*   rp    = (int*)(ws + alloc((size_t)(Nn + 1) * 4));
  int*   srcs  = (int*)(ws + alloc((size_t)Ne * 4));
  int*   gcur  = (int*)(ws + alloc((size_t)NB * 16 * 4));
  int*   payload = (int*)(ws + alloc((size_t)NB * BCAP * 4));
  int*   gp    = (int*)(ws + alloc((size_t)(Bg + 1) * 4));
  float* WihT  = (float*)(ws + alloc((size_t)128 * 256 * 4));
  float* WhhT  = (float*)(ws + alloc((size_t)64 * 256 * 4));
  float* W1T   = (float*)(ws + alloc((size_t)128 * 64 * 4));
  unsigned short* mlp_h = (unsigned short*)(ws + alloc(2048 * 2));
  unsigned short* mlp_l = (unsigned short*)(ws + alloc(2048 * 2));
  unsigned short* cv_h  = (unsigned short*)(ws + alloc(4096 * 2));
  unsigned short* cv_l  = (unsigned short*)(ws + alloc(4096 * 2));
  unsigned short* ih_h  = (unsigned short*)(ws + alloc(18432 * 2));
  unsigned short* ih_l  = (unsigned short*)(ws + alloc(18432 * 2));
  unsigned short* hh_h  = (unsigned short*)(ws + alloc(12288 * 2));
  unsigned short* hh_l  = (unsigned short*)(ws + alloc(12288 * 2));
  float* s2s   = (float*)(ws + alloc((size_t)Bg * (128 + 64 + 64) * 4));
  float* q_star = s2s;
  float* hl     = s2s + Bg * 128;
  float* cl     = s2s + Bg * 128 + Bg * 64;
  (void)in_sizes; (void)n_in; (void)out_size; (void)ws_size;

  hipMemsetAsync(gcur, 0, (size_t)NB * 16 * 4, stream);

  // CSR build (bucket sort) + prep
  k_bucket<<<Ne / 4096, 256, 0, stream>>>(eidx, gcur, payload);
  k_placeB<<<NB, 256, 0, stream>>>(gcur, payload, rp, srcs);
  k_prepw<<<370, 256, 0, stream>>>(W_mlp, W_conv, gW_ih, gW_hh, lW_ih, lW_hh, W1,
                                   mlp_h, mlp_l, cv_h, cv_l, ih_h, ih_l, hh_h, hh_l,
                                   WihT, WhhT, W1T, batch, gp, rp);

  // conv1 (+ x-column planes)
  k_conv1<<<Nn / 64, 256, 0, stream>>>(x, mlp_h, mlp_l, b_mlp, hpAh, hpAl, Aih, Ail);

  unsigned short *cph = hpAh, *cpl = hpAl, *nph = hpBh, *npl = hpBl;
  for (int step = 0; step < 2; ++step) {
    k_lin<<<Nn / 64, 256, 0, stream>>>(cph, cpl, cv_h, cv_l, b_conv, lin);
    k_aggregate<<<Nn * 16 / 256, 256, 0, stream>>>(rp, srcs, lin, Aih, Ail);
    k_gru<<<Nn / 64, 256, 0, stream>>>(Aih, Ail, cph, cpl, ih_h, ih_l, hh_h, hh_l,
                                       gb_ih, gb_hh, nph, npl);
    unsigned short* tu;
    tu = cph; cph = nph; nph = tu;
    tu = cpl; cpl = npl; npl = tu;
  }

  for (int it = 0; it < 3; ++it) {
    k_s2s<<<Bg, 256, 0, stream>>>(cph, cpl, gp, q_star, hl, cl, WihT, WhhT,
                                  lb_ih, lb_hh, W1T, b1, W2, b2, outp,
                                  it == 0 ? 1 : 0, it == 2 ? 1 : 0);
  }
}

// Round 9
// 365.918 us; speedup vs baseline: 1.5433x; 1.0452x over previous
//
#include <hip/hip_runtime.h>
#include <math.h>

constexpr int Nn  = 65536;    // nodes
constexpr int Ne  = 1048576;  // edges
constexpr int Bg  = 256;      // graphs
constexpr int DIN = 32;
constexpr int D   = 64;

constexpr int NB   = 256;     // dst buckets (dst>>8)
constexpr int BCAP = 6144;    // bucket stream capacity (mean 4096, +36 sigma)

typedef __attribute__((ext_vector_type(8))) short bf16x8;
typedef __attribute__((ext_vector_type(4))) float f32x4;

__device__ __forceinline__ float sigf(float x) { return 1.0f / (1.0f + expf(-x)); }

// ---- bf16 split helpers (RNE) ----
__device__ __forceinline__ unsigned short bf16_rne(float f) {
  unsigned u = __float_as_uint(f);
  unsigned r = u + 0x7FFFu + ((u >> 16) & 1u);
  return (unsigned short)(r >> 16);
}
__device__ __forceinline__ float bf16_tof(unsigned short h) {
  return __uint_as_float(((unsigned)h) << 16);
}
__device__ __forceinline__ void split2(float f, unsigned short& hi, unsigned short& lo) {
  hi = bf16_rne(f);
  lo = bf16_rne(f - bf16_tof(hi));
}
__device__ __forceinline__ float recon(unsigned short hi, unsigned short lo) {
  return bf16_tof(hi) + bf16_tof(lo);
}

#define MFMA(a, b, c) __builtin_amdgcn_mfma_f32_16x16x32_bf16(a, b, c, 0, 0, 0)

// ---------------------------------------------------------------------------
// Prep: GRU weights packed CHUNK-MAJOR (5 chunks x 12nt x 64lane x 8j per
// plane; chunks 0..2 = Wih ks, 3..4 = Whh ks) + conv packs + transposes + gp.
// ---------------------------------------------------------------------------
__global__ void k_prepw(const float* __restrict__ W_mlp, const float* __restrict__ W_conv,
                        const float* __restrict__ gWih, const float* __restrict__ gWhh,
                        const float* __restrict__ lW_ih, const float* __restrict__ lW_hh,
                        const float* __restrict__ W1,
                        unsigned short* __restrict__ mlp_h, unsigned short* __restrict__ mlp_l,
                        unsigned short* __restrict__ cv_h,  unsigned short* __restrict__ cv_l,
                        unsigned short* __restrict__ gw_h,  unsigned short* __restrict__ gw_l,
                        float* __restrict__ WihT, float* __restrict__ WhhT,
                        float* __restrict__ W1T,
                        const int* __restrict__ batch, int* __restrict__ gp,
                        int* __restrict__ rp) {
  int idx = blockIdx.x * 256 + threadIdx.x;
  if (idx < 30720) {  // GRU weights, chunk-major
    int c = idx / 6144, rem = idx % 6144;
    int nt = rem >> 9, lane = (rem >> 3) & 63, j = rem & 7;
    int n = nt * 16 + (lane & 15);
    float v;
    if (c < 3) v = gWih[n * 96 + c * 32 + (lane >> 4) * 8 + j];
    else       v = gWhh[n * 64 + (c - 3) * 32 + (lane >> 4) * 8 + j];
    unsigned short hi, lo; split2(v, hi, lo);
    gw_h[idx] = hi; gw_l[idx] = lo;
    return;
  }
  if (idx < 32768) {  // W_mlp (KS=1)
    int lp = idx - 30720;
    int nt = lp >> 9, lane = (lp >> 3) & 63, j = lp & 7;
    int n = nt * 16 + (lane & 15);
    unsigned short hi, lo;
    split2(W_mlp[n * 32 + (lane >> 4) * 8 + j], hi, lo);
    mlp_h[lp] = hi; mlp_l[lp] = lo;
    return;
  }
  if (idx < 36864) {  // W_conv (KS=2), layout ((nt*2+ks)*64+lane)*8+j
    int lp = idx - 32768;
    int q = lp >> 9, lane = (lp >> 3) & 63, j = lp & 7;
    int nt = q >> 1, ks = q & 1;
    int n = nt * 16 + (lane & 15);
    unsigned short hi, lo;
    split2(W_conv[n * 64 + ks * 32 + (lane >> 4) * 8 + j], hi, lo);
    cv_h[lp] = hi; cv_l[lp] = lo;
    return;
  }
  int t = idx - 36864;
  if (t < 32768) {                 // lstm W_ih [256][128] -> WihT [128][256]
    int row = t / 128, k = t % 128;
    WihT[k * 256 + row] = lW_ih[t];
  } else if (t < 49152) {          // lstm W_hh [256][64] -> WhhT [64][256]
    int j = t - 32768;
    int row = j / 64, k = j % 64;
    WhhT[k * 256 + row] = lW_hh[j];
  } else if (t < 57344) {          // W1 [64][128] -> W1T [128][64]
    int j = t - 49152;
    int row = j / 128, k = j % 128;
    W1T[k * 64 + row] = W1[j];
  } else if (t < 57344 + Bg + 1) { // graphptr + rp[Nn]
    int g = t - 57344;
    if (g == 0) rp[Nn] = Ne;
    int lo = 0, hi = Nn;
    while (lo < hi) {
      int mid = (lo + hi) >> 1;
      if (batch[mid] < g) lo = mid + 1; else hi = mid;
    }
    gp[g] = lo;
  }
}

// ---------------------------------------------------------------------------
// conv1: h = x @ W_mlp^T + b  (K=32, N=64). Splits x in-kernel; also fills
// inp96 x-columns (64..95).  h stored as planes only.
// ---------------------------------------------------------------------------
__global__ __launch_bounds__(256) void k_conv1(const float* __restrict__ x,
                                               const unsigned short* __restrict__ Wh,
                                               const unsigned short* __restrict__ Wl,
                                               const float* __restrict__ bias,
                                               unsigned short* __restrict__ hph,
                                               unsigned short* __restrict__ hpl,
                                               unsigned short* __restrict__ Aih,
                                               unsigned short* __restrict__ Ail) {
  int wave = threadIdx.x >> 6, lane = threadIdx.x & 63;
  int quad = lane >> 4;
  int n0w = blockIdx.x * 64 + wave * 16;
  int rowA = n0w + (lane & 15);
  const float4* xp = (const float4*)&x[(size_t)rowA * 32 + quad * 8];
  float4 xa = xp[0], xb = xp[1];
  float xv[8] = {xa.x, xa.y, xa.z, xa.w, xb.x, xb.y, xb.z, xb.w};
  bf16x8 ah, al;
#pragma unroll
  for (int j = 0; j < 8; ++j) {
    unsigned short hi, lo; split2(xv[j], hi, lo);
    ah[j] = (short)hi; al[j] = (short)lo;
  }
  *(bf16x8*)&Aih[(size_t)rowA * 96 + 64 + quad * 8] = ah;
  *(bf16x8*)&Ail[(size_t)rowA * 96 + 64 + quad * 8] = al;

  f32x4 acc[4] = {};
#pragma unroll
  for (int nt = 0; nt < 4; ++nt) {
    bf16x8 bh = *(const bf16x8*)&Wh[(nt * 64 + lane) * 8];
    bf16x8 bl = *(const bf16x8*)&Wl[(nt * 64 + lane) * 8];
    acc[nt] = MFMA(ah, bh, acc[nt]);
    acc[nt] = MFMA(ah, bl, acc[nt]);
    acc[nt] = MFMA(al, bh, acc[nt]);
  }
  int col0 = lane & 15;
#pragma unroll
  for (int nt = 0; nt < 4; ++nt) {
    float bv = bias[nt * 16 + col0];
#pragma unroll
    for (int r = 0; r < 4; ++r) {
      int node = n0w + quad * 4 + r;
      float v = acc[nt][r] + bv;
      size_t o = (size_t)node * 64 + nt * 16 + col0;
      unsigned short hi, lo; split2(v, hi, lo);
      hph[o] = hi; hpl[o] = lo;
    }
  }
}

// ---------------------------------------------------------------------------
// lin = h @ W_conv^T + b  (K=64, N=64).  fp32 out (feeds gather).
// ---------------------------------------------------------------------------
__global__ __launch_bounds__(256) void k_lin(const unsigned short* __restrict__ Ah,
                                             const unsigned short* __restrict__ Al,
                                             const unsigned short* __restrict__ Wh,
                                             const unsigned short* __restrict__ Wl,
                                             const float* __restrict__ bias,
                                             float* __restrict__ lin) {
  int wave = threadIdx.x >> 6, lane = threadIdx.x & 63;
  int quad = lane >> 4;
  int n0w = blockIdx.x * 64 + wave * 16;
  int rowA = n0w + (lane & 15);
  f32x4 acc[4] = {};
#pragma unroll
  for (int ks = 0; ks < 2; ++ks) {
    bf16x8 ah = *(const bf16x8*)&Ah[(size_t)rowA * 64 + ks * 32 + quad * 8];
    bf16x8 al = *(const bf16x8*)&Al[(size_t)rowA * 64 + ks * 32 + quad * 8];
#pragma unroll
    for (int nt = 0; nt < 4; ++nt) {
      bf16x8 bh = *(const bf16x8*)&Wh[((nt * 2 + ks) * 64 + lane) * 8];
      bf16x8 bl = *(const bf16x8*)&Wl[((nt * 2 + ks) * 64 + lane) * 8];
      acc[nt] = MFMA(ah, bh, acc[nt]);
      acc[nt] = MFMA(ah, bl, acc[nt]);
      acc[nt] = MFMA(al, bh, acc[nt]);
    }
  }
  int col0 = lane & 15;
#pragma unroll
  for (int nt = 0; nt < 4; ++nt) {
    float bv = bias[nt * 16 + col0];
#pragma unroll
    for (int r = 0; r < 4; ++r) {
      int node = n0w + quad * 4 + r;
      lin[(size_t)node * 64 + nt * 16 + col0] = acc[nt][r] + bv;
    }
  }
}

// ---------------------------------------------------------------------------
// Fused GRU v3: software-pipelined K-loop.
// 128 nodes/block, each wave M=32 (two 16-row tiles).  5 chunks (3 gi + 2 gh)
// over a double-buffered LDS weight stage: load chunk c+1 to VGPRs, compute
// chunk c (72 MFMAs/wave), write c+1 to the other buffer, ONE barrier/chunk.
// ---------------------------------------------------------------------------
__global__ __launch_bounds__(256, 2) void k_gru(const unsigned short* __restrict__ Aih,
                                                const unsigned short* __restrict__ Ail,
                                                const unsigned short* __restrict__ Hh,
                                                const unsigned short* __restrict__ Hl,
                                                const unsigned short* __restrict__ gw_h,
                                                const unsigned short* __restrict__ gw_l,
                                                const float* __restrict__ b_ih,
                                                const float* __restrict__ b_hh,
                                                unsigned short* __restrict__ nph,
                                                unsigned short* __restrict__ npl) {
  __shared__ unsigned short sW[2][12288];  // per buf: hi[0..6143] | lo[6144..]
  int tid = threadIdx.x;
  int wave = tid >> 6, lane = tid & 63;
  int quad = lane >> 4;
  int n0w = blockIdx.x * 128 + wave * 32;
  int rowA0 = n0w + (lane & 15);          // tile0 A-row; tile1 = +16
  f32x4 acc0[12] = {}, acc1[12] = {};     // gi r,z,n (gh r,z folded into 0..7)
  f32x4 aN0[4] = {}, aN1[4] = {};         // gh n-gate

  bf16x8 gvh[3], gvl[3];
  // prologue: stage chunk 0
#pragma unroll
  for (int j = 0; j < 3; ++j) {
    gvh[j] = *(const bf16x8*)&gw_h[(tid + j * 256) * 8];
    gvl[j] = *(const bf16x8*)&gw_l[(tid + j * 256) * 8];
  }
#pragma unroll
  for (int j = 0; j < 3; ++j) {
    *(bf16x8*)&sW[0][(tid + j * 256) * 8] = gvh[j];
    *(bf16x8*)&sW[0][6144 + (tid + j * 256) * 8] = gvl[j];
  }
  __syncthreads();

#pragma unroll
  for (int c = 0; c < 5; ++c) {
    const int buf = c & 1;
    if (c < 4) {  // prefetch chunk c+1 into VGPRs (in flight during MFMAs)
#pragma unroll
      for (int j = 0; j < 3; ++j) {
        gvh[j] = *(const bf16x8*)&gw_h[(c + 1) * 6144 + (tid + j * 256) * 8];
        gvl[j] = *(const bf16x8*)&gw_l[(c + 1) * 6144 + (tid + j * 256) * 8];
      }
    }
    // A fragments for both tiles
    bf16x8 a0h, a0l, a1h, a1l;
    if (c < 3) {
      size_t b0 = (size_t)rowA0 * 96 + c * 32 + quad * 8;
      size_t b1 = (size_t)(rowA0 + 16) * 96 + c * 32 + quad * 8;
      a0h = *(const bf16x8*)&Aih[b0]; a0l = *(const bf16x8*)&Ail[b0];
      a1h = *(const bf16x8*)&Aih[b1]; a1l = *(const bf16x8*)&Ail[b1];
    } else {
      size_t b0 = (size_t)rowA0 * 64 + (c - 3) * 32 + quad * 8;
      size_t b1 = (size_t)(rowA0 + 16) * 64 + (c - 3) * 32 + quad * 8;
      a0h = *(const bf16x8*)&Hh[b0]; a0l = *(const bf16x8*)&Hl[b0];
      a1h = *(const bf16x8*)&Hh[b1]; a1l = *(const bf16x8*)&Hl[b1];
    }
    const unsigned short* sw = sW[buf];
#pragma unroll
    for (int nt = 0; nt < 12; ++nt) {
      bf16x8 bh = *(const bf16x8*)&sw[(nt * 64 + lane) * 8];
      bf16x8 bl = *(const bf16x8*)&sw[6144 + (nt * 64 + lane) * 8];
      if (c < 3 || nt < 8) {
        acc0[nt] = MFMA(a0h, bh, acc0[nt]);
        acc0[nt] = MFMA(a0h, bl, acc0[nt]);
        acc0[nt] = MFMA(a0l, bh, acc0[nt]);
        acc1[nt] = MFMA(a1h, bh, acc1[nt]);
        acc1[nt] = MFMA(a1h, bl, acc1[nt]);
        acc1[nt] = MFMA(a1l, bh, acc1[nt]);
      } else {
        aN0[nt - 8] = MFMA(a0h, bh, aN0[nt - 8]);
        aN0[nt - 8] = MFMA(a0h, bl, aN0[nt - 8]);
        aN0[nt - 8] = MFMA(a0l, bh, aN0[nt - 8]);
        aN1[nt - 8] = MFMA(a1h, bh, aN1[nt - 8]);
        aN1[nt - 8] = MFMA(a1h, bl, aN1[nt - 8]);
        aN1[nt - 8] = MFMA(a1l, bh, aN1[nt - 8]);
      }
    }
    if (c < 4) {  // write prefetched chunk into the other buffer
#pragma unroll
      for (int j = 0; j < 3; ++j) {
        *(bf16x8*)&sW[1 - buf][(tid + j * 256) * 8] = gvh[j];
        *(bf16x8*)&sW[1 - buf][6144 + (tid + j * 256) * 8] = gvl[j];
      }
    }
    __syncthreads();
  }

  // epilogue: GRU nonlinearity + plane store, both tiles
  int col0 = lane & 15;
#pragma unroll
  for (int tile = 0; tile < 2; ++tile) {
    int nb = n0w + tile * 16;
#pragma unroll
    for (int nt = 0; nt < 4; ++nt) {
      float br  = b_ih[nt * 16 + col0]       + b_hh[nt * 16 + col0];
      float bz  = b_ih[64 + nt * 16 + col0]  + b_hh[64 + nt * 16 + col0];
      float bin = b_ih[128 + nt * 16 + col0];
      float bhn = b_hh[128 + nt * 16 + col0];
#pragma unroll
      for (int r = 0; r < 4; ++r) {
        int node = nb + quad * 4 + r;
        size_t o = (size_t)node * 64 + nt * 16 + col0;
        float gr = tile ? acc1[nt][r]     : acc0[nt][r];
        float gz = tile ? acc1[nt + 4][r] : acc0[nt + 4][r];
        float gn = tile ? acc1[nt + 8][r] : acc0[nt + 8][r];
        float hn = tile ? aN1[nt][r]      : aN0[nt][r];
        float rr = sigf(gr + br);
        float zz = sigf(gz + bz);
        float nn = tanhf(gn + bin + rr * (hn + bhn));
        float h_old = recon(Hh[o], Hl[o]);
        float hv = (1.f - zz) * nn + zz * h_old;
        unsigned short hi, lo; split2(hv, hi, lo);
        nph[o] = hi; npl[o] = lo;
      }
    }
  }
}

// ---------------------------------------------------------------------------
// CSR build v3: two-level bucket sort by dst.
// ---------------------------------------------------------------------------
__global__ __launch_bounds__(256) void k_bucket(const int* __restrict__ eidx,
                                                int* __restrict__ gcur,     // [NB*16]
                                                int* __restrict__ payload) {// [NB*BCAP]
  __shared__ int lcnt[NB];
  __shared__ int lcur[NB];
  int t = threadIdx.x;
  int e0 = blockIdx.x * 4096;
  lcnt[t] = 0;
  __syncthreads();
  int ds[16], ss[16];
#pragma unroll
  for (int i = 0; i < 16; ++i) {
    int e = e0 + i * 256 + t;
    ds[i] = eidx[Ne + e];
    ss[i] = eidx[e];
    atomicAdd(&lcnt[ds[i] >> 8], 1);
  }
  __syncthreads();
  lcur[t] = atomicAdd(&gcur[t * 16], lcnt[t]);  // reserve contiguous run
  __syncthreads();
#pragma unroll
  for (int i = 0; i < 16; ++i) {
    int b = ds[i] >> 8;
    int p = atomicAdd(&lcur[b], 1);
    if (p < BCAP) payload[b * BCAP + p] = (ss[i] << 8) | (ds[i] & 255);
  }
}

// One block per bucket: inline scan of gcur -> base, LDS hist -> rp slice,
// place srcs via LDS cursors (scatter window owned by one CU).
__global__ __launch_bounds__(256) void k_placeB(const int* __restrict__ gcur,
                                                const int* __restrict__ payload,
                                                int* __restrict__ rp,
                                                int* __restrict__ srcs) {
  __shared__ int sAll[NB];
  __shared__ int hst[NB];
  __shared__ int cur[NB];
  int b = blockIdx.x, t = threadIdx.x;
  sAll[t] = gcur[t * 16];
  hst[t] = 0;
  __syncthreads();
  int cnt = min(sAll[b], BCAP);
  for (int off = 1; off < NB; off <<= 1) {
    int v = (t >= off) ? sAll[t - off] : 0;
    __syncthreads();
    sAll[t] += v;
    __syncthreads();
  }
  int base = sAll[b] - gcur[b * 16];  // exclusive prefix (true counts)
  const int* pay = &payload[b * BCAP];
  for (int i = t; i < cnt; i += 256) atomicAdd(&hst[pay[i] & 255], 1);
  __syncthreads();
  int c = hst[t];
  cur[t] = c;
  __syncthreads();
  for (int off = 1; off < NB; off <<= 1) {
    int v = (t >= off) ? cur[t - off] : 0;
    __syncthreads();
    cur[t] += v;
    __syncthreads();
  }
  int excl = cur[t] - c;
  rp[b * 256 + t] = base + excl;
  cur[t] = base + excl;
  __syncthreads();
  for (int i = t; i < cnt; i += 256) {
    int pl = pay[i];
    int p = atomicAdd(&cur[pl & 255], 1);
    srcs[p] = pl >> 8;
  }
}

// ---------------------------------------------------------------------------
// CSR aggregate: m[n] = sum over in-edges of lin[src]; writes split planes.
// ---------------------------------------------------------------------------
__global__ void k_aggregate(const int* __restrict__ rp, const int* __restrict__ srcs,
                            const float* __restrict__ lin,
                            unsigned short* __restrict__ Aih,
                            unsigned short* __restrict__ Ail) {
  int t = blockIdx.x * 256 + threadIdx.x;
  int n = t >> 4;
  int q = t & 15;
  int s = rp[n], e = rp[n + 1];
  float4 acc = {0.f, 0.f, 0.f, 0.f};
  for (int i = s; i < e; ++i) {
    int src = srcs[i];
    float4 v = *(const float4*)&lin[(size_t)src * 64 + q * 4];
    acc.x += v.x; acc.y += v.y; acc.z += v.z; acc.w += v.w;
  }
  ushort4 h4, l4;
  split2(acc.x, h4.x, l4.x);
  split2(acc.y, h4.y, l4.y);
  split2(acc.z, h4.z, l4.z);
  split2(acc.w, h4.w, l4.w);
  *(ushort4*)&Aih[(size_t)n * 96 + q * 4] = h4;
  *(ushort4*)&Ail[(size_t)n * 96 + q * 4] = l4;
}

// ---------------------------------------------------------------------------
// Fused Set2Set iteration: LSTM cell + attention (+ optional head).
// ---------------------------------------------------------------------------
constexpr int ACAP = 1024;  // max nodes per graph (dataset max ~330)
__global__ __launch_bounds__(256) void k_s2s(const unsigned short* __restrict__ hph,
                                             const unsigned short* __restrict__ hpl,
                                             const int* __restrict__ gp,
                                             float* __restrict__ q_star,
                                             float* __restrict__ hl,
                                             float* __restrict__ cl,
                                             const float* __restrict__ WihT,
                                             const float* __restrict__ WhhT,
                                             const float* __restrict__ b_ih,
                                             const float* __restrict__ b_hh,
                                             const float* __restrict__ W1T,
                                             const float* __restrict__ b1,
                                             const float* __restrict__ W2,
                                             const float* __restrict__ b2,
                                             float* __restrict__ outp,
                                             int first, int do_head) {
  int g = blockIdx.x;
  int t = threadIdx.x;
  int w = t >> 6, lane = t & 63;
  __shared__ float qs[128], hsh[64], gates[256];
  __shared__ float qsh[64], rsh[64];
  __shared__ float eL[ACAP];
  __shared__ float red[4];
  __shared__ float partial[4][64];
  __shared__ float asum_p[4];
  __shared__ float emax_sh;
  __shared__ float l4[4];

  // ---- LSTM cell ----
  if (t < 128) qs[t] = first ? 0.f : q_star[g * 128 + t];
  else if (t < 192) hsh[t - 128] = first ? 0.f : hl[g * 64 + (t - 128)];
  __syncthreads();
  {
    float acc = b_ih[t] + b_hh[t];
    for (int k = 0; k < 128; ++k) acc = fmaf(WihT[k * 256 + t], qs[k], acc);
    for (int k = 0; k < 64; ++k)  acc = fmaf(WhhT[k * 256 + t], hsh[k], acc);
    gates[t] = acc;
  }
  __syncthreads();
  if (t < 64) {
    float ig = sigf(gates[t]),        fg = sigf(gates[64 + t]);
    float gg = tanhf(gates[128 + t]), og = sigf(gates[192 + t]);
    float c_old = first ? 0.f : cl[g * 64 + t];
    float c = fg * c_old + ig * gg;
    float q = og * tanhf(c);
    cl[g * 64 + t] = c;
    hl[g * 64 + t] = q;
    q_star[g * 128 + t] = q;
    qsh[t] = q;
  }
  __syncthreads();

  int s = gp[g], e = gp[g + 1];
  int cnt = e - s;

  // ---- attention phase A: e_i = h[i].q ----
  int c4 = (lane & 15) * 4;
  float4 qv = {qsh[c4], qsh[c4 + 1], qsh[c4 + 2], qsh[c4 + 3]};
  for (int i0 = s + w * 4; i0 < e; i0 += 16) {
    int node = i0 + (lane >> 4);
    float p = 0.f;
    if (node < e) {
      ushort4 h4 = *(const ushort4*)&hph[(size_t)node * 64 + c4];
      ushort4 l4v = *(const ushort4*)&hpl[(size_t)node * 64 + c4];
      p = recon(h4.x, l4v.x) * qv.x + recon(h4.y, l4v.y) * qv.y +
          recon(h4.z, l4v.z) * qv.z + recon(h4.w, l4v.w) * qv.w;
    }
    p += __shfl_xor(p, 1); p += __shfl_xor(p, 2);
    p += __shfl_xor(p, 4); p += __shfl_xor(p, 8);
    if (node < e && (lane & 15) == 0) eL[node - s] = p;
  }
  __syncthreads();

  // ---- phase B: segment max ----
  float m = -INFINITY;
  for (int i = t; i < cnt; i += 256) m = fmaxf(m, eL[i]);
#pragma unroll
  for (int o = 32; o >= 1; o >>= 1) m = fmaxf(m, __shfl_xor(m, o));
  if (lane == 0) red[w] = m;
  __syncthreads();
  if (t == 0) {
    float mm = fmaxf(fmaxf(red[0], red[1]), fmaxf(red[2], red[3]));
    emax_sh = isfinite(mm) ? mm : 0.f;
  }
  __syncthreads();
  float emax = emax_sh;

  // ---- phase C: softmax-weighted feature sum ----
  float acc = 0.f, asum = 0.f;
  for (int i = s + w; i < e; i += 4) {
    float a = expf(eL[i - s] - emax);
    asum += a;
    float hv = recon(hph[(size_t)i * 64 + lane], hpl[(size_t)i * 64 + lane]);
    acc = fmaf(a, hv, acc);
  }
  partial[w][lane] = acc;
  if (lane == 0) asum_p[w] = asum;
  __syncthreads();
  if (t < 64) {
    float r  = partial[0][t] + partial[1][t] + partial[2][t] + partial[3][t];
    float as = asum_p[0] + asum_p[1] + asum_p[2] + asum_p[3];
    float rv = (cnt > 0) ? r / fmaxf(as, 1e-16f) : 0.f;
    q_star[g * 128 + 64 + t] = rv;
    rsh[t] = rv;
  }
  if (!do_head) return;
  __syncthreads();

  // ---- head ----
  if (t < 64) {
    float a1 = b1[t];
    for (int k = 0; k < 64; ++k)  a1 = fmaf(W1T[k * 64 + t], qsh[k], a1);
    for (int k = 64; k < 128; ++k) a1 = fmaf(W1T[k * 64 + t], rsh[k - 64], a1);
    hsh[t] = fmaxf(a1, 0.f);
  }
  __syncthreads();
  if (t < 4) {
    float lg = b2[t];
    for (int d = 0; d < 64; ++d) lg = fmaf(W2[t * 64 + d], hsh[d], lg);
    l4[t] = lg;
  }
  __syncthreads();
  if (t < 4) {
    float mx = fmaxf(fmaxf(l4[0], l4[1]), fmaxf(l4[2], l4[3]));
    float ssum = expf(l4[0] - mx) + expf(l4[1] - mx) + expf(l4[2] - mx) + expf(l4[3] - mx);
    outp[g * 4 + t] = l4[t] - mx - logf(ssum);
  }
}

// ---------------------------------------------------------------------------
extern "C" void kernel_launch(void* const* d_in, const int* in_sizes, int n_in,
                              void* d_out, int out_size, void* d_ws, size_t ws_size,
                              hipStream_t stream) {
  const float* x        = (const float*)d_in[0];
  const int*   eidx     = (const int*)d_in[1];
  const int*   batch    = (const int*)d_in[2];
  const float* W_mlp    = (const float*)d_in[3];
  const float* b_mlp    = (const float*)d_in[4];
  const float* W_conv   = (const float*)d_in[5];
  const float* b_conv   = (const float*)d_in[6];
  const float* gW_ih    = (const float*)d_in[7];
  const float* gW_hh    = (const float*)d_in[8];
  const float* gb_ih    = (const float*)d_in[9];
  const float* gb_hh    = (const float*)d_in[10];
  const float* lW_ih    = (const float*)d_in[11];
  const float* lW_hh    = (const float*)d_in[12];
  const float* lb_ih    = (const float*)d_in[13];
  const float* lb_hh    = (const float*)d_in[14];
  const float* W1       = (const float*)d_in[15];
  const float* b1       = (const float*)d_in[16];
  const float* W2       = (const float*)d_in[17];
  const float* b2       = (const float*)d_in[18];
  float* outp = (float*)d_out;

  // ---- workspace layout ----
  char* ws = (char*)d_ws;
  size_t off = 0;
  auto alloc = [&](size_t bytes) { size_t r = off; off = (off + bytes + 255) & ~(size_t)255; return r; };
  unsigned short* hpAh = (unsigned short*)(ws + alloc((size_t)Nn * 64 * 2));
  unsigned short* hpAl = (unsigned short*)(ws + alloc((size_t)Nn * 64 * 2));
  unsigned short* hpBh = (unsigned short*)(ws + alloc((size_t)Nn * 64 * 2));
  unsigned short* hpBl = (unsigned short*)(ws + alloc((size_t)Nn * 64 * 2));
  unsigned short* Aih  = (unsigned short*)(ws + alloc((size_t)Nn * 96 * 2));
  unsigned short* Ail  = (unsigned short*)(ws + alloc((size_t)Nn * 96 * 2));
  float* lin   = (float*)(ws + alloc((size_t)Nn * 64 * 4));
  int*   rp    = (int*)(ws + alloc((size_t)(Nn + 1) * 4));
  int*   srcs  = (int*)(ws + alloc((size_t)Ne * 4));
  int*   gcur  = (int*)(ws + alloc((size_t)NB * 16 * 4));
  int*   payload = (int*)(ws + alloc((size_t)NB * BCAP * 4));
  int*   gp    = (int*)(ws + alloc((size_t)(Bg + 1) * 4));
  float* WihT  = (float*)(ws + alloc((size_t)128 * 256 * 4));
  float* WhhT  = (float*)(ws + alloc((size_t)64 * 256 * 4));
  float* W1T   = (float*)(ws + alloc((size_t)128 * 64 * 4));
  unsigned short* mlp_h = (unsigned short*)(ws + alloc(2048 * 2));
  unsigned short* mlp_l = (unsigned short*)(ws + alloc(2048 * 2));
  unsigned short* cv_h  = (unsigned short*)(ws + alloc(4096 * 2));
  unsigned short* cv_l  = (unsigned short*)(ws + alloc(4096 * 2));
  unsigned short* gw_h  = (unsigned short*)(ws + alloc(30720 * 2));
  unsigned short* gw_l  = (unsigned short*)(ws + alloc(30720 * 2));
  float* s2s   = (float*)(ws + alloc((size_t)Bg * (128 + 64 + 64) * 4));
  float* q_star = s2s;
  float* hl     = s2s + Bg * 128;
  float* cl     = s2s + Bg * 128 + Bg * 64;
  (void)in_sizes; (void)n_in; (void)out_size; (void)ws_size;

  hipMemsetAsync(gcur, 0, (size_t)NB * 16 * 4, stream);

  // CSR build (bucket sort) + prep
  k_bucket<<<Ne / 4096, 256, 0, stream>>>(eidx, gcur, payload);
  k_placeB<<<NB, 256, 0, stream>>>(gcur, payload, rp, srcs);
  k_prepw<<<370, 256, 0, stream>>>(W_mlp, W_conv, gW_ih, gW_hh, lW_ih, lW_hh, W1,
                                   mlp_h, mlp_l, cv_h, cv_l, gw_h, gw_l,
                                   WihT, WhhT, W1T, batch, gp, rp);

  // conv1 (+ x-column planes)
  k_conv1<<<Nn / 64, 256, 0, stream>>>(x, mlp_h, mlp_l, b_mlp, hpAh, hpAl, Aih, Ail);

  unsigned short *cph = hpAh, *cpl = hpAl, *nph = hpBh, *npl = hpBl;
  for (int step = 0; step < 2; ++step) {
    k_lin<<<Nn / 64, 256, 0, stream>>>(cph, cpl, cv_h, cv_l, b_conv, lin);
    k_aggregate<<<Nn * 16 / 256, 256, 0, stream>>>(rp, srcs, lin, Aih, Ail);
    k_gru<<<Nn / 128, 256, 0, stream>>>(Aih, Ail, cph, cpl, gw_h, gw_l,
                                        gb_ih, gb_hh, nph, npl);
    unsigned short* tu;
    tu = cph; cph = nph; nph = tu;
    tu = cpl; cpl = npl; npl = tu;
  }

  for (int it = 0; it < 3; ++it) {
    k_s2s<<<Bg, 256, 0, stream>>>(cph, cpl, gp, q_star, hl, cl, WihT, WhhT,
                                  lb_ih, lb_hh, W1T, b1, W2, b2, outp,
                                  it == 0 ? 1 : 0, it == 2 ? 1 : 0);
  }
}

// Round 10
// 350.230 us; speedup vs baseline: 1.6124x; 1.0448x over previous
//
#include <hip/hip_runtime.h>
#include <math.h>

constexpr int Nn  = 65536;    // nodes
constexpr int Ne  = 1048576;  // edges
constexpr int Bg  = 256;      // graphs
constexpr int DIN = 32;
constexpr int D   = 64;

constexpr int NB   = 256;     // dst buckets (dst>>8)
constexpr int BCAP = 6144;    // bucket stream capacity (mean 4096, +36 sigma)

typedef __attribute__((ext_vector_type(8))) short bf16x8;
typedef __attribute__((ext_vector_type(4))) float f32x4;

__device__ __forceinline__ float sigf(float x) { return 1.0f / (1.0f + expf(-x)); }

// ---- bf16 split helpers (RNE) ----
__device__ __forceinline__ unsigned short bf16_rne(float f) {
  unsigned u = __float_as_uint(f);
  unsigned r = u + 0x7FFFu + ((u >> 16) & 1u);
  return (unsigned short)(r >> 16);
}
__device__ __forceinline__ float bf16_tof(unsigned short h) {
  return __uint_as_float(((unsigned)h) << 16);
}
__device__ __forceinline__ void split2(float f, unsigned short& hi, unsigned short& lo) {
  hi = bf16_rne(f);
  lo = bf16_rne(f - bf16_tof(hi));
}
__device__ __forceinline__ float recon(unsigned short hi, unsigned short lo) {
  return bf16_tof(hi) + bf16_tof(lo);
}

#define MFMA(a, b, c) __builtin_amdgcn_mfma_f32_16x16x32_bf16(a, b, c, 0, 0, 0)

// ---------------------------------------------------------------------------
// Prep.  GRU weights chunk-major (5 chunks x 12nt x 64lane x 8j / plane):
//   chunks 0,1 = Wfold = Wih[:, :64] @ W_conv   (fused conv-linear!)
//   chunk  2   = Wih[:, 64:96]  (x part)
//   chunks 3,4 = Whh
// Also: W_mlp pack, LSTM/W1 transposes, graphptr, rp[Nn],
// vfold[g] = dot(Wih[g, :64], b_conv).
// ---------------------------------------------------------------------------
__global__ void k_prepw(const float* __restrict__ W_mlp, const float* __restrict__ W_conv,
                        const float* __restrict__ gWih, const float* __restrict__ gWhh,
                        const float* __restrict__ b_conv,
                        const float* __restrict__ lW_ih, const float* __restrict__ lW_hh,
                        const float* __restrict__ W1,
                        unsigned short* __restrict__ mlp_h, unsigned short* __restrict__ mlp_l,
                        unsigned short* __restrict__ gw_h,  unsigned short* __restrict__ gw_l,
                        float* __restrict__ WihT, float* __restrict__ WhhT,
                        float* __restrict__ W1T, float* __restrict__ vfold,
                        const int* __restrict__ batch, int* __restrict__ gp,
                        int* __restrict__ rp) {
  int idx = blockIdx.x * 256 + threadIdx.x;
  if (idx < 30720) {  // GRU weights, chunk-major
    int c = idx / 6144, rem = idx % 6144;
    int nt = rem >> 9, lane = (rem >> 3) & 63, j = rem & 7;
    int n = nt * 16 + (lane & 15);
    int kk = c * 32 + (lane >> 4) * 8 + j;   // for c<3: k index into [S|x]
    float v;
    if (c < 2) {        // Wfold[n][kk] = sum_o Wih[n][o] * W_conv[o][kk]
      float s = 0.f;
      for (int o = 0; o < 64; ++o) s = fmaf(gWih[n * 96 + o], W_conv[o * 64 + kk], s);
      v = s;
    } else if (c == 2) {
      v = gWih[n * 96 + kk];                 // kk in 64..95 (x columns)
    } else {
      v = gWhh[n * 64 + (c - 3) * 32 + (lane >> 4) * 8 + j];
    }
    unsigned short hi, lo; split2(v, hi, lo);
    gw_h[idx] = hi; gw_l[idx] = lo;
    return;
  }
  if (idx < 32768) {  // W_mlp (KS=1)
    int lp = idx - 30720;
    int nt = lp >> 9, lane = (lp >> 3) & 63, j = lp & 7;
    int n = nt * 16 + (lane & 15);
    unsigned short hi, lo;
    split2(W_mlp[n * 32 + (lane >> 4) * 8 + j], hi, lo);
    mlp_h[lp] = hi; mlp_l[lp] = lo;
    return;
  }
  int t = idx - 32768;
  if (t < 32768) {                 // lstm W_ih [256][128] -> WihT [128][256]
    int row = t / 128, k = t % 128;
    WihT[k * 256 + row] = lW_ih[t];
  } else if (t < 49152) {          // lstm W_hh [256][64] -> WhhT [64][256]
    int j = t - 32768;
    int row = j / 64, k = j % 64;
    WhhT[k * 256 + row] = lW_hh[j];
  } else if (t < 57344) {          // W1 [64][128] -> W1T [128][64]
    int j = t - 49152;
    int row = j / 128, k = j % 128;
    W1T[k * 64 + row] = W1[j];
  } else if (t < 57344 + Bg + 1) { // graphptr + rp[Nn]
    int g = t - 57344;
    if (g == 0) rp[Nn] = Ne;
    int lo = 0, hi = Nn;
    while (lo < hi) {
      int mid = (lo + hi) >> 1;
      if (batch[mid] < g) lo = mid + 1; else hi = mid;
    }
    gp[g] = lo;
  } else if (t < 57344 + 257 + 192) { // vfold[192]
    int g = t - 57344 - 257;
    float s = 0.f;
    for (int o = 0; o < 64; ++o) s = fmaf(gWih[g * 96 + o], b_conv[o], s);
    vfold[g] = s;
  }
}

// ---------------------------------------------------------------------------
// conv1: h = x @ W_mlp^T + b  (K=32, N=64). Splits x in-kernel; also fills
// inp96 x-columns (64..95).  h stored as planes only.
// ---------------------------------------------------------------------------
__global__ __launch_bounds__(256) void k_conv1(const float* __restrict__ x,
                                               const unsigned short* __restrict__ Wh,
                                               const unsigned short* __restrict__ Wl,
                                               const float* __restrict__ bias,
                                               unsigned short* __restrict__ hph,
                                               unsigned short* __restrict__ hpl,
                                               unsigned short* __restrict__ Aih,
                                               unsigned short* __restrict__ Ail) {
  int wave = threadIdx.x >> 6, lane = threadIdx.x & 63;
  int quad = lane >> 4;
  int n0w = blockIdx.x * 64 + wave * 16;
  int rowA = n0w + (lane & 15);
  const float4* xp = (const float4*)&x[(size_t)rowA * 32 + quad * 8];
  float4 xa = xp[0], xb = xp[1];
  float xv[8] = {xa.x, xa.y, xa.z, xa.w, xb.x, xb.y, xb.z, xb.w};
  bf16x8 ah, al;
#pragma unroll
  for (int j = 0; j < 8; ++j) {
    unsigned short hi, lo; split2(xv[j], hi, lo);
    ah[j] = (short)hi; al[j] = (short)lo;
  }
  *(bf16x8*)&Aih[(size_t)rowA * 96 + 64 + quad * 8] = ah;
  *(bf16x8*)&Ail[(size_t)rowA * 96 + 64 + quad * 8] = al;

  f32x4 acc[4] = {};
#pragma unroll
  for (int nt = 0; nt < 4; ++nt) {
    bf16x8 bh = *(const bf16x8*)&Wh[(nt * 64 + lane) * 8];
    bf16x8 bl = *(const bf16x8*)&Wl[(nt * 64 + lane) * 8];
    acc[nt] = MFMA(ah, bh, acc[nt]);
    acc[nt] = MFMA(ah, bl, acc[nt]);
    acc[nt] = MFMA(al, bh, acc[nt]);
  }
  int col0 = lane & 15;
#pragma unroll
  for (int nt = 0; nt < 4; ++nt) {
    float bv = bias[nt * 16 + col0];
#pragma unroll
    for (int r = 0; r < 4; ++r) {
      int node = n0w + quad * 4 + r;
      float v = acc[nt][r] + bv;
      size_t o = (size_t)node * 64 + nt * 16 + col0;
      unsigned short hi, lo; split2(v, hi, lo);
      hph[o] = hi; hpl[o] = lo;
    }
  }
}

// ---------------------------------------------------------------------------
// Fused GRU v4: software-pipelined K-loop + folded conv bias (deg * vfold).
// 128 nodes/block, wave M=32.  5 chunks over double-buffered LDS weights.
// ---------------------------------------------------------------------------
__global__ __launch_bounds__(256, 2) void k_gru(const unsigned short* __restrict__ Aih,
                                                const unsigned short* __restrict__ Ail,
                                                const unsigned short* __restrict__ Hh,
                                                const unsigned short* __restrict__ Hl,
                                                const unsigned short* __restrict__ gw_h,
                                                const unsigned short* __restrict__ gw_l,
                                                const float* __restrict__ b_ih,
                                                const float* __restrict__ b_hh,
                                                const float* __restrict__ vfold,
                                                const int* __restrict__ rp,
                                                unsigned short* __restrict__ nph,
                                                unsigned short* __restrict__ npl) {
  __shared__ unsigned short sW[2][12288];  // per buf: hi[0..6143] | lo[6144..]
  int tid = threadIdx.x;
  int wave = tid >> 6, lane = tid & 63;
  int quad = lane >> 4;
  int n0w = blockIdx.x * 128 + wave * 32;
  int rowA0 = n0w + (lane & 15);          // tile0 A-row; tile1 = +16
  f32x4 acc0[12] = {}, acc1[12] = {};     // gi r,z,n (gh r,z folded into 0..7)
  f32x4 aN0[4] = {}, aN1[4] = {};         // gh n-gate

  bf16x8 gvh[3], gvl[3];
#pragma unroll
  for (int j = 0; j < 3; ++j) {
    gvh[j] = *(const bf16x8*)&gw_h[(tid + j * 256) * 8];
    gvl[j] = *(const bf16x8*)&gw_l[(tid + j * 256) * 8];
  }
#pragma unroll
  for (int j = 0; j < 3; ++j) {
    *(bf16x8*)&sW[0][(tid + j * 256) * 8] = gvh[j];
    *(bf16x8*)&sW[0][6144 + (tid + j * 256) * 8] = gvl[j];
  }
  __syncthreads();

#pragma unroll
  for (int c = 0; c < 5; ++c) {
    const int buf = c & 1;
    if (c < 4) {
#pragma unroll
      for (int j = 0; j < 3; ++j) {
        gvh[j] = *(const bf16x8*)&gw_h[(c + 1) * 6144 + (tid + j * 256) * 8];
        gvl[j] = *(const bf16x8*)&gw_l[(c + 1) * 6144 + (tid + j * 256) * 8];
      }
    }
    bf16x8 a0h, a0l, a1h, a1l;
    if (c < 3) {
      size_t b0 = (size_t)rowA0 * 96 + c * 32 + quad * 8;
      size_t b1 = (size_t)(rowA0 + 16) * 96 + c * 32 + quad * 8;
      a0h = *(const bf16x8*)&Aih[b0]; a0l = *(const bf16x8*)&Ail[b0];
      a1h = *(const bf16x8*)&Aih[b1]; a1l = *(const bf16x8*)&Ail[b1];
    } else {
      size_t b0 = (size_t)rowA0 * 64 + (c - 3) * 32 + quad * 8;
      size_t b1 = (size_t)(rowA0 + 16) * 64 + (c - 3) * 32 + quad * 8;
      a0h = *(const bf16x8*)&Hh[b0]; a0l = *(const bf16x8*)&Hl[b0];
      a1h = *(const bf16x8*)&Hh[b1]; a1l = *(const bf16x8*)&Hl[b1];
    }
    const unsigned short* sw = sW[buf];
#pragma unroll
    for (int nt = 0; nt < 12; ++nt) {
      bf16x8 bh = *(const bf16x8*)&sw[(nt * 64 + lane) * 8];
      bf16x8 bl = *(const bf16x8*)&sw[6144 + (nt * 64 + lane) * 8];
      if (c < 3 || nt < 8) {
        acc0[nt] = MFMA(a0h, bh, acc0[nt]);
        acc0[nt] = MFMA(a0h, bl, acc0[nt]);
        acc0[nt] = MFMA(a0l, bh, acc0[nt]);
        acc1[nt] = MFMA(a1h, bh, acc1[nt]);
        acc1[nt] = MFMA(a1h, bl, acc1[nt]);
        acc1[nt] = MFMA(a1l, bh, acc1[nt]);
      } else {
        aN0[nt - 8] = MFMA(a0h, bh, aN0[nt - 8]);
        aN0[nt - 8] = MFMA(a0h, bl, aN0[nt - 8]);
        aN0[nt - 8] = MFMA(a0l, bh, aN0[nt - 8]);
        aN1[nt - 8] = MFMA(a1h, bh, aN1[nt - 8]);
        aN1[nt - 8] = MFMA(a1h, bl, aN1[nt - 8]);
        aN1[nt - 8] = MFMA(a1l, bh, aN1[nt - 8]);
      }
    }
    if (c < 4) {
#pragma unroll
      for (int j = 0; j < 3; ++j) {
        *(bf16x8*)&sW[1 - buf][(tid + j * 256) * 8] = gvh[j];
        *(bf16x8*)&sW[1 - buf][6144 + (tid + j * 256) * 8] = gvl[j];
      }
    }
    __syncthreads();
  }

  // epilogue: GRU nonlinearity + deg*vfold (folded conv bias) + plane store
  int col0 = lane & 15;
#pragma unroll
  for (int tile = 0; tile < 2; ++tile) {
    int nb = n0w + tile * 16;
#pragma unroll
    for (int r = 0; r < 4; ++r) {
      int node = nb + quad * 4 + r;
      float degf = (float)(rp[node + 1] - rp[node]);
#pragma unroll
      for (int nt = 0; nt < 4; ++nt) {
        int g = nt * 16 + col0;
        size_t o = (size_t)node * 64 + g;
        float br  = b_ih[g] + b_hh[g] + degf * vfold[g];
        float bz  = b_ih[64 + g] + b_hh[64 + g] + degf * vfold[64 + g];
        float bin = b_ih[128 + g] + degf * vfold[128 + g];
        float bhn = b_hh[128 + g];
        float gr = tile ? acc1[nt][r]     : acc0[nt][r];
        float gz = tile ? acc1[nt + 4][r] : acc0[nt + 4][r];
        float gn = tile ? acc1[nt + 8][r] : acc0[nt + 8][r];
        float hn = tile ? aN1[nt][r]      : aN0[nt][r];
        float rr = sigf(gr + br);
        float zz = sigf(gz + bz);
        float nn = tanhf(gn + bin + rr * (hn + bhn));
        float h_old = recon(Hh[o], Hl[o]);
        float hv = (1.f - zz) * nn + zz * h_old;
        unsigned short hi, lo; split2(hv, hi, lo);
        nph[o] = hi; npl[o] = lo;
      }
    }
  }
}

// ---------------------------------------------------------------------------
// CSR build v3: two-level bucket sort by dst.
// ---------------------------------------------------------------------------
__global__ __launch_bounds__(256) void k_bucket(const int* __restrict__ eidx,
                                                int* __restrict__ gcur,     // [NB*16]
                                                int* __restrict__ payload) {// [NB*BCAP]
  __shared__ int lcnt[NB];
  __shared__ int lcur[NB];
  int t = threadIdx.x;
  int e0 = blockIdx.x * 4096;
  lcnt[t] = 0;
  __syncthreads();
  int ds[16], ss[16];
#pragma unroll
  for (int i = 0; i < 16; ++i) {
    int e = e0 + i * 256 + t;
    ds[i] = eidx[Ne + e];
    ss[i] = eidx[e];
    atomicAdd(&lcnt[ds[i] >> 8], 1);
  }
  __syncthreads();
  lcur[t] = atomicAdd(&gcur[t * 16], lcnt[t]);  // reserve contiguous run
  __syncthreads();
#pragma unroll
  for (int i = 0; i < 16; ++i) {
    int b = ds[i] >> 8;
    int p = atomicAdd(&lcur[b], 1);
    if (p < BCAP) payload[b * BCAP + p] = (ss[i] << 8) | (ds[i] & 255);
  }
}

// One block per bucket: inline scan of gcur -> base, LDS hist -> rp slice,
// place srcs via LDS cursors (scatter window owned by one CU).
__global__ __launch_bounds__(256) void k_placeB(const int* __restrict__ gcur,
                                                const int* __restrict__ payload,
                                                int* __restrict__ rp,
                                                int* __restrict__ srcs) {
  __shared__ int sAll[NB];
  __shared__ int hst[NB];
  __shared__ int cur[NB];
  int b = blockIdx.x, t = threadIdx.x;
  sAll[t] = gcur[t * 16];
  hst[t] = 0;
  __syncthreads();
  int cnt = min(sAll[b], BCAP);
  for (int off = 1; off < NB; off <<= 1) {
    int v = (t >= off) ? sAll[t - off] : 0;
    __syncthreads();
    sAll[t] += v;
    __syncthreads();
  }
  int base = sAll[b] - gcur[b * 16];  // exclusive prefix (true counts)
  const int* pay = &payload[b * BCAP];
  for (int i = t; i < cnt; i += 256) atomicAdd(&hst[pay[i] & 255], 1);
  __syncthreads();
  int c = hst[t];
  cur[t] = c;
  __syncthreads();
  for (int off = 1; off < NB; off <<= 1) {
    int v = (t >= off) ? cur[t - off] : 0;
    __syncthreads();
    cur[t] += v;
    __syncthreads();
  }
  int excl = cur[t] - c;
  rp[b * 256 + t] = base + excl;
  cur[t] = base + excl;
  __syncthreads();
  for (int i = t; i < cnt; i += 256) {
    int pl = pay[i];
    int p = atomicAdd(&cur[pl & 255], 1);
    srcs[p] = pl >> 8;
  }
}

// ---------------------------------------------------------------------------
// Aggregate v2: S[n] = sum over in-edges of h[src] (h from planes).
// One WAVE per node: 4 lane-groups walk every-4th edge concurrently (4x MLP),
// cross-group shuffle reduce.  W_conv folded into the GRU weights.
// ---------------------------------------------------------------------------
__global__ __launch_bounds__(256) void k_aggregate(const int* __restrict__ rp,
                                                   const int* __restrict__ srcs,
                                                   const unsigned short* __restrict__ Hh,
                                                   const unsigned short* __restrict__ Hl,
                                                   unsigned short* __restrict__ Aih,
                                                   unsigned short* __restrict__ Ail) {
  int n = (blockIdx.x * 256 + threadIdx.x) >> 6;
  int lane = threadIdx.x & 63;
  int grp = lane >> 4, q = lane & 15;
  int s = rp[n], e = rp[n + 1];
  float4 acc = {0.f, 0.f, 0.f, 0.f};
  for (int i = s + grp; i < e; i += 4) {
    int src = srcs[i];
    ushort4 h4 = *(const ushort4*)&Hh[(size_t)src * 64 + q * 4];
    ushort4 l4 = *(const ushort4*)&Hl[(size_t)src * 64 + q * 4];
    acc.x += recon(h4.x, l4.x);
    acc.y += recon(h4.y, l4.y);
    acc.z += recon(h4.z, l4.z);
    acc.w += recon(h4.w, l4.w);
  }
#pragma unroll
  for (int o = 16; o <= 32; o <<= 1) {
    acc.x += __shfl_xor(acc.x, o);
    acc.y += __shfl_xor(acc.y, o);
    acc.z += __shfl_xor(acc.z, o);
    acc.w += __shfl_xor(acc.w, o);
  }
  if (grp == 0) {
    ushort4 h4, l4;
    split2(acc.x, h4.x, l4.x);
    split2(acc.y, h4.y, l4.y);
    split2(acc.z, h4.z, l4.z);
    split2(acc.w, h4.w, l4.w);
    *(ushort4*)&Aih[(size_t)n * 96 + q * 4] = h4;
    *(ushort4*)&Ail[(size_t)n * 96 + q * 4] = l4;
  }
}

// ---------------------------------------------------------------------------
// Fused Set2Set iteration: LSTM cell + attention (+ optional head).
// ---------------------------------------------------------------------------
constexpr int ACAP = 1024;  // max nodes per graph (dataset max ~330)
__global__ __launch_bounds__(256) void k_s2s(const unsigned short* __restrict__ hph,
                                             const unsigned short* __restrict__ hpl,
                                             const int* __restrict__ gp,
                                             float* __restrict__ q_star,
                                             float* __restrict__ hl,
                                             float* __restrict__ cl,
                                             const float* __restrict__ WihT,
                                             const float* __restrict__ WhhT,
                                             const float* __restrict__ b_ih,
                                             const float* __restrict__ b_hh,
                                             const float* __restrict__ W1T,
                                             const float* __restrict__ b1,
                                             const float* __restrict__ W2,
                                             const float* __restrict__ b2,
                                             float* __restrict__ outp,
                                             int first, int do_head) {
  int g = blockIdx.x;
  int t = threadIdx.x;
  int w = t >> 6, lane = t & 63;
  __shared__ float qs[128], hsh[64], gates[256];
  __shared__ float qsh[64], rsh[64];
  __shared__ float eL[ACAP];
  __shared__ float red[4];
  __shared__ float partial[4][64];
  __shared__ float asum_p[4];
  __shared__ float emax_sh;
  __shared__ float l4[4];

  // ---- LSTM cell ----
  if (t < 128) qs[t] = first ? 0.f : q_star[g * 128 + t];
  else if (t < 192) hsh[t - 128] = first ? 0.f : hl[g * 64 + (t - 128)];
  __syncthreads();
  {
    float acc = b_ih[t] + b_hh[t];
    for (int k = 0; k < 128; ++k) acc = fmaf(WihT[k * 256 + t], qs[k], acc);
    for (int k = 0; k < 64; ++k)  acc = fmaf(WhhT[k * 256 + t], hsh[k], acc);
    gates[t] = acc;
  }
  __syncthreads();
  if (t < 64) {
    float ig = sigf(gates[t]),        fg = sigf(gates[64 + t]);
    float gg = tanhf(gates[128 + t]), og = sigf(gates[192 + t]);
    float c_old = first ? 0.f : cl[g * 64 + t];
    float c = fg * c_old + ig * gg;
    float q = og * tanhf(c);
    cl[g * 64 + t] = c;
    hl[g * 64 + t] = q;
    q_star[g * 128 + t] = q;
    qsh[t] = q;
  }
  __syncthreads();

  int s = gp[g], e = gp[g + 1];
  int cnt = e - s;

  // ---- attention phase A: e_i = h[i].q ----
  int c4 = (lane & 15) * 4;
  float4 qv = {qsh[c4], qsh[c4 + 1], qsh[c4 + 2], qsh[c4 + 3]};
  for (int i0 = s + w * 4; i0 < e; i0 += 16) {
    int node = i0 + (lane >> 4);
    float p = 0.f;
    if (node < e) {
      ushort4 h4 = *(const ushort4*)&hph[(size_t)node * 64 + c4];
      ushort4 l4v = *(const ushort4*)&hpl[(size_t)node * 64 + c4];
      p = recon(h4.x, l4v.x) * qv.x + recon(h4.y, l4v.y) * qv.y +
          recon(h4.z, l4v.z) * qv.z + recon(h4.w, l4v.w) * qv.w;
    }
    p += __shfl_xor(p, 1); p += __shfl_xor(p, 2);
    p += __shfl_xor(p, 4); p += __shfl_xor(p, 8);
    if (node < e && (lane & 15) == 0) eL[node - s] = p;
  }
  __syncthreads();

  // ---- phase B: segment max ----
  float m = -INFINITY;
  for (int i = t; i < cnt; i += 256) m = fmaxf(m, eL[i]);
#pragma unroll
  for (int o = 32; o >= 1; o >>= 1) m = fmaxf(m, __shfl_xor(m, o));
  if (lane == 0) red[w] = m;
  __syncthreads();
  if (t == 0) {
    float mm = fmaxf(fmaxf(red[0], red[1]), fmaxf(red[2], red[3]));
    emax_sh = isfinite(mm) ? mm : 0.f;
  }
  __syncthreads();
  float emax = emax_sh;

  // ---- phase C: softmax-weighted feature sum ----
  float acc = 0.f, asum = 0.f;
  for (int i = s + w; i < e; i += 4) {
    float a = expf(eL[i - s] - emax);
    asum += a;
    float hv = recon(hph[(size_t)i * 64 + lane], hpl[(size_t)i * 64 + lane]);
    acc = fmaf(a, hv, acc);
  }
  partial[w][lane] = acc;
  if (lane == 0) asum_p[w] = asum;
  __syncthreads();
  if (t < 64) {
    float r  = partial[0][t] + partial[1][t] + partial[2][t] + partial[3][t];
    float as = asum_p[0] + asum_p[1] + asum_p[2] + asum_p[3];
    float rv = (cnt > 0) ? r / fmaxf(as, 1e-16f) : 0.f;
    q_star[g * 128 + 64 + t] = rv;
    rsh[t] = rv;
  }
  if (!do_head) return;
  __syncthreads();

  // ---- head ----
  if (t < 64) {
    float a1 = b1[t];
    for (int k = 0; k < 64; ++k)  a1 = fmaf(W1T[k * 64 + t], qsh[k], a1);
    for (int k = 64; k < 128; ++k) a1 = fmaf(W1T[k * 64 + t], rsh[k - 64], a1);
    hsh[t] = fmaxf(a1, 0.f);
  }
  __syncthreads();
  if (t < 4) {
    float lg = b2[t];
    for (int d = 0; d < 64; ++d) lg = fmaf(W2[t * 64 + d], hsh[d], lg);
    l4[t] = lg;
  }
  __syncthreads();
  if (t < 4) {
    float mx = fmaxf(fmaxf(l4[0], l4[1]), fmaxf(l4[2], l4[3]));
    float ssum = expf(l4[0] - mx) + expf(l4[1] - mx) + expf(l4[2] - mx) + expf(l4[3] - mx);
    outp[g * 4 + t] = l4[t] - mx - logf(ssum);
  }
}

// ---------------------------------------------------------------------------
extern "C" void kernel_launch(void* const* d_in, const int* in_sizes, int n_in,
                              void* d_out, int out_size, void* d_ws, size_t ws_size,
                              hipStream_t stream) {
  const float* x        = (const float*)d_in[0];
  const int*   eidx     = (const int*)d_in[1];
  const int*   batch    = (const int*)d_in[2];
  const float* W_mlp    = (const float*)d_in[3];
  const float* b_mlp    = (const float*)d_in[4];
  const float* W_conv   = (const float*)d_in[5];
  const float* b_conv   = (const float*)d_in[6];
  const float* gW_ih    = (const float*)d_in[7];
  const float* gW_hh    = (const float*)d_in[8];
  const float* gb_ih    = (const float*)d_in[9];
  const float* gb_hh    = (const float*)d_in[10];
  const float* lW_ih    = (const float*)d_in[11];
  const float* lW_hh    = (const float*)d_in[12];
  const float* lb_ih    = (const float*)d_in[13];
  const float* lb_hh    = (const float*)d_in[14];
  const float* W1       = (const float*)d_in[15];
  const float* b1       = (const float*)d_in[16];
  const float* W2       = (const float*)d_in[17];
  const float* b2       = (const float*)d_in[18];
  float* outp = (float*)d_out;

  // ---- workspace layout ----
  char* ws = (char*)d_ws;
  size_t off = 0;
  auto alloc = [&](size_t bytes) { size_t r = off; off = (off + bytes + 255) & ~(size_t)255; return r; };
  unsigned short* hpAh = (unsigned short*)(ws + alloc((size_t)Nn * 64 * 2));
  unsigned short* hpAl = (unsigned short*)(ws + alloc((size_t)Nn * 64 * 2));
  unsigned short* hpBh = (unsigned short*)(ws + alloc((size_t)Nn * 64 * 2));
  unsigned short* hpBl = (unsigned short*)(ws + alloc((size_t)Nn * 64 * 2));
  unsigned short* Aih  = (unsigned short*)(ws + alloc((size_t)Nn * 96 * 2));
  unsigned short* Ail  = (unsigned short*)(ws + alloc((size_t)Nn * 96 * 2));
  int*   rp    = (int*)(ws + alloc((size_t)(Nn + 1) * 4));
  int*   srcs  = (int*)(ws + alloc((size_t)Ne * 4));
  int*   gcur  = (int*)(ws + alloc((size_t)NB * 16 * 4));
  int*   payload = (int*)(ws + alloc((size_t)NB * BCAP * 4));
  int*   gp    = (int*)(ws + alloc((size_t)(Bg + 1) * 4));
  float* WihT  = (float*)(ws + alloc((size_t)128 * 256 * 4));
  float* WhhT  = (float*)(ws + alloc((size_t)64 * 256 * 4));
  float* W1T   = (float*)(ws + alloc((size_t)128 * 64 * 4));
  float* vfold = (float*)(ws + alloc(192 * 4));
  unsigned short* mlp_h = (unsigned short*)(ws + alloc(2048 * 2));
  unsigned short* mlp_l = (unsigned short*)(ws + alloc(2048 * 2));
  unsigned short* gw_h  = (unsigned short*)(ws + alloc(30720 * 2));
  unsigned short* gw_l  = (unsigned short*)(ws + alloc(30720 * 2));
  float* s2s   = (float*)(ws + alloc((size_t)Bg * (128 + 64 + 64) * 4));
  float* q_star = s2s;
  float* hl     = s2s + Bg * 128;
  float* cl     = s2s + Bg * 128 + Bg * 64;
  (void)in_sizes; (void)n_in; (void)out_size; (void)ws_size;

  hipMemsetAsync(gcur, 0, (size_t)NB * 16 * 4, stream);

  // CSR build (bucket sort) + prep (incl. W_conv folding)
  k_bucket<<<Ne / 4096, 256, 0, stream>>>(eidx, gcur, payload);
  k_placeB<<<NB, 256, 0, stream>>>(gcur, payload, rp, srcs);
  k_prepw<<<355, 256, 0, stream>>>(W_mlp, W_conv, gW_ih, gW_hh, b_conv,
                                   lW_ih, lW_hh, W1,
                                   mlp_h, mlp_l, gw_h, gw_l,
                                   WihT, WhhT, W1T, vfold, batch, gp, rp);

  // conv1 (+ x-column planes)
  k_conv1<<<Nn / 64, 256, 0, stream>>>(x, mlp_h, mlp_l, b_mlp, hpAh, hpAl, Aih, Ail);

  unsigned short *cph = hpAh, *cpl = hpAl, *nph = hpBh, *npl = hpBl;
  for (int step = 0; step < 2; ++step) {
    k_aggregate<<<Nn / 4, 256, 0, stream>>>(rp, srcs, cph, cpl, Aih, Ail);
    k_gru<<<Nn / 128, 256, 0, stream>>>(Aih, Ail, cph, cpl, gw_h, gw_l,
                                        gb_ih, gb_hh, vfold, rp, nph, npl);
    unsigned short* tu;
    tu = cph; cph = nph; nph = tu;
    tu = cpl; cpl = npl; npl = tu;
  }

  for (int it = 0; it < 3; ++it) {
    k_s2s<<<Bg, 256, 0, stream>>>(cph, cpl, gp, q_star, hl, cl, WihT, WhhT,
                                  lb_ih, lb_hh, W1T, b1, W2, b2, outp,
                                  it == 0 ? 1 : 0, it == 2 ? 1 : 0);
  }
}